// Round 4
// baseline (804.993 us; speedup 1.0000x reference)
//
#include <hip/hip_runtime.h>
#include <hip/hip_bf16.h>

// ---------------- small helpers ----------------
__device__ __forceinline__ float4 f4_fma(float4 a, float s, float4 acc) {
    acc.x = fmaf(a.x, s, acc.x); acc.y = fmaf(a.y, s, acc.y);
    acc.z = fmaf(a.z, s, acc.z); acc.w = fmaf(a.w, s, acc.w);
    return acc;
}
__device__ __forceinline__ float4 f4_add(float4 a, float4 b) {
    return make_float4(a.x + b.x, a.y + b.y, a.z + b.z, a.w + b.w);
}

typedef const __attribute__((address_space(1))) unsigned int* gas_u32;
typedef __attribute__((address_space(3))) unsigned int* las_u32;

__device__ __forceinline__ void gl_lds16(const float* g, float* l) {
    __builtin_amdgcn_global_load_lds((gas_u32)(const void*)g, (las_u32)(void*)l, 16, 0, 0);
}

// ---------------- degree / norm ----------------
__global__ __launch_bounds__(256) void cnt_count_kernel(const int* __restrict__ dst, int* cnt, int E) {
    int i = blockIdx.x * blockDim.x + threadIdx.x;
    if (i < E) atomicAdd(&cnt[dst[i]], 1);
}

__global__ __launch_bounds__(256) void dinv_kernel(const int* __restrict__ cnt, float* dinv, int N) {
    int i = blockIdx.x * blockDim.x + threadIdx.x;
    if (i < N) dinv[i] = rsqrtf((float)(cnt[i] + 1));  // +1 self-loop
}

// ---------------- exclusive scan (N ~ 100k) ----------------
#define SCAN_CHUNK 4096  // 256 threads * 16

__global__ __launch_bounds__(256) void scan_reduce_kernel(const int* __restrict__ cnt, int* bsum, int N) {
    __shared__ int sdata[256];
    int base = blockIdx.x * SCAN_CHUNK;
    int s = 0;
    for (int k = 0; k < 16; ++k) {
        int i = base + k * 256 + threadIdx.x;
        if (i < N) s += cnt[i];
    }
    sdata[threadIdx.x] = s;
    __syncthreads();
    for (int off = 128; off > 0; off >>= 1) {
        if (threadIdx.x < off) sdata[threadIdx.x] += sdata[threadIdx.x + off];
        __syncthreads();
    }
    if (threadIdx.x == 0) bsum[blockIdx.x] = sdata[0];
}

__global__ void scan_bsum_kernel(int* bsum, int B) {
    if (threadIdx.x == 0 && blockIdx.x == 0) {
        int run = 0;
        for (int i = 0; i < B; ++i) { int v = bsum[i]; bsum[i] = run; run += v; }
    }
}

__global__ __launch_bounds__(256) void scan_write_kernel(const int* __restrict__ cnt,
                                                         const int* __restrict__ bsum,
                                                         int* rowptr, int N) {
    __shared__ int sdata[256];
    int base = blockIdx.x * SCAN_CHUNK;
    int tbase = base + threadIdx.x * 16;
    int loc[16];
    int s = 0;
    for (int k = 0; k < 16; ++k) {
        int i = tbase + k;
        int v = (i < N) ? cnt[i] : 0;
        loc[k] = s; s += v;
    }
    sdata[threadIdx.x] = s;
    __syncthreads();
    for (int off = 1; off < 256; off <<= 1) {
        int v = sdata[threadIdx.x];
        int add = (threadIdx.x >= off) ? sdata[threadIdx.x - off] : 0;
        __syncthreads();
        sdata[threadIdx.x] = v + add;
        __syncthreads();
    }
    int texcl = (threadIdx.x == 0) ? 0 : sdata[threadIdx.x - 1];
    int boff = bsum[blockIdx.x];
    for (int k = 0; k < 16; ++k) {
        int i = tbase + k;
        if (i < N) rowptr[i] = boff + texcl + loc[k];
    }
}

__global__ __launch_bounds__(256) void cursor_init_kernel(const int* __restrict__ rowptr,
                                                          int* cursor, int* rowptr_end,
                                                          int N, int E) {
    int i = blockIdx.x * blockDim.x + threadIdx.x;
    if (i < N) cursor[i] = rowptr[i];
    if (i == N) *rowptr_end = E;  // rowptr[N] = E
}

// col-only fill (edge weights folded into pre-scaled t' and epilogue dinv[v])
__global__ __launch_bounds__(256) void csr_fill_kernel(const int* __restrict__ src,
                                                       const int* __restrict__ dst,
                                                       int* cursor, int* __restrict__ col,
                                                       int E) {
    int e = blockIdx.x * blockDim.x + threadIdx.x;
    if (e >= E) return;
    int s = src[e], d = dst[e];
    int pos = atomicAdd(&cursor[d], 1);
    col[pos] = s;
}

// ---------------- register-tiled GEMM: t[N][128] = (h[N][128] @ W[128][128]) * dinv[row] ----------------
// 256 threads, tile = 64 rows x 128 cols. Thread: 8 rows x 4 cols acc.
// W fully in LDS (64 KB); h tile double-buffered (2x32 KB) via global_load_lds.
#define TILE_R 64

__global__ __launch_bounds__(256) void gemm128_tiled(const float* __restrict__ h,
                                                     const float* __restrict__ Wa,
                                                     const float* __restrict__ Wb,
                                                     const float* __restrict__ dinv,
                                                     float* __restrict__ t,
                                                     int N, int ntiles) {
    __shared__ float Wl[128 * 128];
    __shared__ float hl[2][TILE_R * 128];

    // stage W (once per block)
    for (int i = threadIdx.x; i < 128 * 128; i += 256) {
        int k = i >> 7, j = i & 127;
        float w = Wb ? ((j < 64) ? Wa[k * 64 + j] : Wb[k * 64 + (j - 64)]) : Wa[i];
        Wl[i] = w;
    }

    const int lane = threadIdx.x & 63;
    const int wav  = threadIdx.x >> 6;   // 0..3
    const int jf4  = threadIdx.x & 31;   // float4 col index
    const int rg   = threadIdx.x >> 5;   // 0..7 (rows rg*8..rg*8+7)

    auto stage = [&](int buf, long long tile) {
        if (tile >= ntiles) return;
        long long row0 = tile * TILE_R;
        if (row0 + TILE_R <= N) {
            const float* gbase = h + row0 * 128 + (size_t)wav * (16 * 128) + lane * 4;
            float* lbase = &hl[buf][wav * (16 * 128)];
            #pragma unroll
            for (int m = 0; m < 8; ++m)
                gl_lds16(gbase + m * 256, lbase + m * 256);
        } else {
            for (int i = threadIdx.x; i < TILE_R * 32; i += 256) {
                int rl = i >> 5, k4 = i & 31;
                long long row = row0 + rl;
                float4 v = (row < N) ? ((const float4*)h)[row * 32 + k4]
                                     : make_float4(0.f, 0.f, 0.f, 0.f);
                *(float4*)&hl[buf][rl * 128 + k4 * 4] = v;
            }
        }
    };

    long long tile = blockIdx.x;
    stage(0, tile);
    __syncthreads();
    int cur = 0;

    for (; tile < ntiles; tile += gridDim.x) {
        stage(cur ^ 1, tile + gridDim.x);  // prefetch next tile into other buffer

        float4 acc[8];
        #pragma unroll
        for (int rr = 0; rr < 8; ++rr) acc[rr] = make_float4(0.f, 0.f, 0.f, 0.f);

        const float* hb = &hl[cur][rg * 8 * 128];
        #pragma unroll 4
        for (int k = 0; k < 128; k += 4) {
            float4 w0 = *(const float4*)&Wl[(k + 0) * 128 + jf4 * 4];
            float4 w1 = *(const float4*)&Wl[(k + 1) * 128 + jf4 * 4];
            float4 w2 = *(const float4*)&Wl[(k + 2) * 128 + jf4 * 4];
            float4 w3 = *(const float4*)&Wl[(k + 3) * 128 + jf4 * 4];
            #pragma unroll
            for (int rr = 0; rr < 8; ++rr) {
                float4 hv = *(const float4*)&hb[rr * 128 + k];
                acc[rr] = f4_fma(w0, hv.x, acc[rr]);
                acc[rr] = f4_fma(w1, hv.y, acc[rr]);
                acc[rr] = f4_fma(w2, hv.z, acc[rr]);
                acc[rr] = f4_fma(w3, hv.w, acc[rr]);
            }
        }

        long long row0 = tile * TILE_R;
        #pragma unroll
        for (int rr = 0; rr < 8; ++rr) {
            long long row = row0 + rg * 8 + rr;
            if (row < N) {
                float di = dinv[row];
                float4 r = acc[rr];
                r.x *= di; r.y *= di; r.z *= di; r.w *= di;
                ((float4*)t)[row * 32 + jf4] = r;
            }
        }
        __syncthreads();
        cur ^= 1;
    }
}

// ---------------- pull aggregation ----------------
// t' is pre-scaled by dinv[src]; out[v] = dinv[v]*(sum t'[col[e]] + t'[v]) + b ; optional relu
__global__ __launch_bounds__(256) void agg_pull_kernel(const float4* __restrict__ t4,
                                                       const int* __restrict__ rowptr,
                                                       const int* __restrict__ col,
                                                       const float* __restrict__ dinv,
                                                       const float* __restrict__ b,
                                                       float4* __restrict__ out4,
                                                       int N, int relu) {
    int v = blockIdx.x * 8 + (threadIdx.x >> 5);
    int c = threadIdx.x & 31;
    if (v >= N) return;
    int beg = rowptr[v], end = rowptr[v + 1];
    float4 acc0 = t4[(size_t)v * 32 + c];  // self-loop (already dinv[v]-scaled)
    float4 acc1 = make_float4(0.f, 0.f, 0.f, 0.f);
    float4 acc2 = make_float4(0.f, 0.f, 0.f, 0.f);
    float4 acc3 = make_float4(0.f, 0.f, 0.f, 0.f);
    int e = beg;
    for (; e + 3 < end; e += 4) {
        int s0 = col[e], s1 = col[e + 1], s2 = col[e + 2], s3 = col[e + 3];
        acc0 = f4_add(acc0, t4[(size_t)s0 * 32 + c]);
        acc1 = f4_add(acc1, t4[(size_t)s1 * 32 + c]);
        acc2 = f4_add(acc2, t4[(size_t)s2 * 32 + c]);
        acc3 = f4_add(acc3, t4[(size_t)s3 * 32 + c]);
    }
    for (; e < end; ++e) acc0 = f4_add(acc0, t4[(size_t)col[e] * 32 + c]);
    float di = dinv[v];
    float4 s = f4_add(f4_add(acc0, acc1), f4_add(acc2, acc3));
    float4 bb = ((const float4*)b)[c];
    float4 r = f4_fma(s, di, bb);
    if (relu) {
        r.x = fmaxf(r.x, 0.f); r.y = fmaxf(r.y, 0.f);
        r.z = fmaxf(r.z, 0.f); r.w = fmaxf(r.w, 0.f);
    }
    out4[(size_t)v * 32 + c] = r;
}

// final layer: cols 0..63 -> mu, 64..127 -> logstd (split output)
__global__ __launch_bounds__(256) void agg_pull_final_kernel(const float4* __restrict__ t4,
                                                             const int* __restrict__ rowptr,
                                                             const int* __restrict__ col,
                                                             const float* __restrict__ dinv,
                                                             const float* __restrict__ bmu,
                                                             const float* __restrict__ bls,
                                                             float4* __restrict__ out4,
                                                             int N) {
    int v = blockIdx.x * 8 + (threadIdx.x >> 5);
    int c = threadIdx.x & 31;
    if (v >= N) return;
    int half = c >> 4, cc = c & 15;
    int beg = rowptr[v], end = rowptr[v + 1];
    float4 acc0 = t4[(size_t)v * 32 + c];
    float4 acc1 = make_float4(0.f, 0.f, 0.f, 0.f);
    float4 acc2 = make_float4(0.f, 0.f, 0.f, 0.f);
    float4 acc3 = make_float4(0.f, 0.f, 0.f, 0.f);
    int e = beg;
    for (; e + 3 < end; e += 4) {
        int s0 = col[e], s1 = col[e + 1], s2 = col[e + 2], s3 = col[e + 3];
        acc0 = f4_add(acc0, t4[(size_t)s0 * 32 + c]);
        acc1 = f4_add(acc1, t4[(size_t)s1 * 32 + c]);
        acc2 = f4_add(acc2, t4[(size_t)s2 * 32 + c]);
        acc3 = f4_add(acc3, t4[(size_t)s3 * 32 + c]);
    }
    for (; e < end; ++e) acc0 = f4_add(acc0, t4[(size_t)col[e] * 32 + c]);
    float di = dinv[v];
    float4 s = f4_add(f4_add(acc0, acc1), f4_add(acc2, acc3));
    float4 bb = half ? ((const float4*)bls)[cc] : ((const float4*)bmu)[cc];
    out4[(size_t)half * N * 16 + (size_t)v * 16 + cc] = f4_fma(s, di, bb);
}

// ---------------- fallback (atomic scatter) kernels ----------------
__global__ __launch_bounds__(256) void deg_init_kernel(float* deg, int N) {
    int i = blockIdx.x * blockDim.x + threadIdx.x;
    if (i < N) deg[i] = 1.0f;
}
__global__ __launch_bounds__(256) void deg_count_kernel(const int* __restrict__ dst, float* deg, int E) {
    int i = blockIdx.x * blockDim.x + threadIdx.x;
    if (i < E) unsafeAtomicAdd(&deg[dst[i]], 1.0f);
}
__global__ __launch_bounds__(256) void deg_rsqrt_kernel(float* deg, int N) {
    int i = blockIdx.x * blockDim.x + threadIdx.x;
    if (i < N) deg[i] = rsqrtf(deg[i]);
}
__global__ __launch_bounds__(256) void gemm128_kernel(const float* __restrict__ h,
                                                      const float* __restrict__ Wa,
                                                      const float* __restrict__ Wb,
                                                      float* __restrict__ t,
                                                      int N, int relu) {
    __shared__ float Wl[128 * 128];
    __shared__ float hl[2][128];
    for (int i = threadIdx.x; i < 128 * 128; i += 256) {
        int k = i >> 7, j = i & 127;
        float w;
        if (Wb) w = (j < 64) ? Wa[k * 64 + j] : Wb[k * 64 + (j - 64)];
        else    w = Wa[i];
        Wl[i] = w;
    }
    __syncthreads();
    int col = threadIdx.x & 127;
    int r   = threadIdx.x >> 7;
    for (long long pair = blockIdx.x; pair * 2 < N; pair += gridDim.x) {
        int row0 = (int)(pair * 2);
        {
            int rr = threadIdx.x >> 7, k = threadIdx.x & 127;
            int row = row0 + rr;
            float v = (row < N) ? h[(size_t)row * 128 + k] : 0.0f;
            if (relu) v = fmaxf(v, 0.0f);
            hl[rr][k] = v;
        }
        __syncthreads();
        float acc = 0.0f;
        #pragma unroll
        for (int k = 0; k < 128; k += 4) {
            float4 hv = *(const float4*)&hl[r][k];
            acc += hv.x * Wl[(k + 0) * 128 + col];
            acc += hv.y * Wl[(k + 1) * 128 + col];
            acc += hv.z * Wl[(k + 2) * 128 + col];
            acc += hv.w * Wl[(k + 3) * 128 + col];
        }
        int row = row0 + r;
        if (row < N) t[(size_t)row * 128 + col] = acc;
        __syncthreads();
    }
}
__global__ __launch_bounds__(256) void init_self_kernel(const float4* __restrict__ t4,
                                                        const float* __restrict__ dinv,
                                                        const float* __restrict__ b,
                                                        float4* __restrict__ out, int N) {
    int idx = blockIdx.x * blockDim.x + threadIdx.x;
    int v = idx >> 5, c = idx & 31;
    if (v >= N) return;
    float di = dinv[v];
    float s = di * di;
    float4 x = t4[(size_t)v * 32 + c];
    float4 bb = ((const float4*)b)[c];
    out[(size_t)v * 32 + c] = make_float4(fmaf(x.x, s, bb.x), fmaf(x.y, s, bb.y),
                                          fmaf(x.z, s, bb.z), fmaf(x.w, s, bb.w));
}
__global__ __launch_bounds__(256) void init_final_kernel(const float4* __restrict__ t4,
                                                         const float* __restrict__ dinv,
                                                         const float* __restrict__ bmu,
                                                         const float* __restrict__ bls,
                                                         float4* __restrict__ out4, int N) {
    int idx = blockIdx.x * blockDim.x + threadIdx.x;
    int v = idx >> 5, c = idx & 31;
    if (v >= N) return;
    int half = c >> 4, cc = c & 15;
    float di = dinv[v];
    float s = di * di;
    float4 x = t4[(size_t)v * 32 + c];
    float4 bb = half ? ((const float4*)bls)[cc] : ((const float4*)bmu)[cc];
    out4[(size_t)half * N * 16 + (size_t)v * 16 + cc] =
        make_float4(fmaf(x.x, s, bb.x), fmaf(x.y, s, bb.y),
                    fmaf(x.z, s, bb.z), fmaf(x.w, s, bb.w));
}
__global__ __launch_bounds__(256) void agg_edge_kernel(const float4* __restrict__ t4,
                                                       const int* __restrict__ src,
                                                       const int* __restrict__ dst,
                                                       const float* __restrict__ dinv,
                                                       float* __restrict__ out, int E) {
    int idx = blockIdx.x * blockDim.x + threadIdx.x;
    int e = idx >> 5, c = idx & 31;
    if (e >= E) return;
    int s = src[e], d = dst[e];
    float w = dinv[s] * dinv[d];
    float4 v = t4[(size_t)s * 32 + c];
    float* o = out + (size_t)d * 128 + c * 4;
    unsafeAtomicAdd(o + 0, v.x * w);
    unsafeAtomicAdd(o + 1, v.y * w);
    unsafeAtomicAdd(o + 2, v.z * w);
    unsafeAtomicAdd(o + 3, v.w * w);
}
__global__ __launch_bounds__(256) void agg_edge_final_kernel(const float4* __restrict__ t4,
                                                             const int* __restrict__ src,
                                                             const int* __restrict__ dst,
                                                             const float* __restrict__ dinv,
                                                             float* __restrict__ out, int N, int E) {
    int idx = blockIdx.x * blockDim.x + threadIdx.x;
    int e = idx >> 5, c = idx & 31;
    if (e >= E) return;
    int s = src[e], d = dst[e];
    int half = c >> 4, cc = c & 15;
    float w = dinv[s] * dinv[d];
    float4 v = t4[(size_t)s * 32 + c];
    float* o = out + (size_t)half * N * 64 + (size_t)d * 64 + cc * 4;
    unsafeAtomicAdd(o + 0, v.x * w);
    unsafeAtomicAdd(o + 1, v.y * w);
    unsafeAtomicAdd(o + 2, v.z * w);
    unsafeAtomicAdd(o + 3, v.w * w);
}

// ---------------- launch ----------------
extern "C" void kernel_launch(void* const* d_in, const int* in_sizes, int n_in,
                              void* d_out, int out_size, void* d_ws, size_t ws_size,
                              hipStream_t stream) {
    const float* x   = (const float*)d_in[0];
    const int*   ei  = (const int*)d_in[1];
    const float* W1  = (const float*)d_in[2];
    const float* b1  = (const float*)d_in[3];
    const float* W2  = (const float*)d_in[4];
    const float* b2  = (const float*)d_in[5];
    const float* Wmu = (const float*)d_in[6];
    const float* bmu = (const float*)d_in[7];
    const float* Wls = (const float*)d_in[8];
    const float* bls = (const float*)d_in[9];

    const int N = in_sizes[0] / 128;
    const int E = in_sizes[1] / 2;
    const int* src = ei;
    const int* dst = ei + E;

    float* out = (float*)d_out;  // reused as h1/h2 buffer

    auto align256 = [](size_t o) { return (o + 255) & ~(size_t)255; };
    const int B1 = (N + SCAN_CHUNK - 1) / SCAN_CHUNK;

    size_t off = 0;
    size_t o_dinv   = off; off = align256(off + (size_t)N * 4);
    size_t o_t      = off; off = align256(off + (size_t)N * 128 * 4);
    size_t o_rowptr = off; off = align256(off + (size_t)(N + 1) * 4);
    size_t o_cursor = off; off = align256(off + (size_t)N * 4);       // also cnt
    size_t o_bsum   = off; off = align256(off + (size_t)B1 * 4);
    size_t o_col    = off; off = align256(off + (size_t)E * 4);
    size_t need = off;

    float* dinv = (float*)((char*)d_ws + o_dinv);
    float* t    = (float*)((char*)d_ws + o_t);

    const int TB = 256;
    int gN = (N + TB - 1) / TB;
    int gE = (E + TB - 1) / TB;
    int ntiles = (N + TILE_R - 1) / TILE_R;

    if (ws_size >= need) {
        int* rowptr = (int*)((char*)d_ws + o_rowptr);
        int* cursor = (int*)((char*)d_ws + o_cursor);
        int* bsum   = (int*)((char*)d_ws + o_bsum);
        int* col    = (int*)((char*)d_ws + o_col);

        // CSR build (col-only; weights folded into t' pre-scale + epilogue)
        hipMemsetAsync(cursor, 0, (size_t)N * 4, stream);
        cnt_count_kernel<<<gE, TB, 0, stream>>>(dst, cursor, E);
        dinv_kernel<<<gN, TB, 0, stream>>>(cursor, dinv, N);
        scan_reduce_kernel<<<B1, TB, 0, stream>>>(cursor, bsum, N);
        scan_bsum_kernel<<<1, 64, 0, stream>>>(bsum, B1);
        scan_write_kernel<<<B1, TB, 0, stream>>>(cursor, bsum, rowptr, N);
        cursor_init_kernel<<<(N + TB) / TB, TB, 0, stream>>>(rowptr, cursor, rowptr + N, N, E);
        csr_fill_kernel<<<gE, TB, 0, stream>>>(src, dst, cursor, col, E);

        int gPull = (N + 7) / 8;
        // layer 1
        gemm128_tiled<<<256, TB, 0, stream>>>(x, W1, nullptr, dinv, t, N, ntiles);
        agg_pull_kernel<<<gPull, TB, 0, stream>>>((const float4*)t, rowptr, col, dinv, b1, (float4*)out, N, 1);
        // layer 2
        gemm128_tiled<<<256, TB, 0, stream>>>(out, W2, nullptr, dinv, t, N, ntiles);
        agg_pull_kernel<<<gPull, TB, 0, stream>>>((const float4*)t, rowptr, col, dinv, b2, (float4*)out, N, 1);
        // layer 3+4 fused
        gemm128_tiled<<<256, TB, 0, stream>>>(out, Wmu, Wls, dinv, t, N, ntiles);
        agg_pull_final_kernel<<<gPull, TB, 0, stream>>>((const float4*)t, rowptr, col, dinv, bmu, bls, (float4*)out, N);
    } else {
        // fallback: atomic scatter path
        int gN32  = (N * 32 + TB - 1) / TB;
        int gE32h = (int)(((long long)E * 32 + TB - 1) / TB);
        deg_init_kernel<<<gN, TB, 0, stream>>>(dinv, N);
        deg_count_kernel<<<gE, TB, 0, stream>>>(dst, dinv, E);
        deg_rsqrt_kernel<<<gN, TB, 0, stream>>>(dinv, N);

        gemm128_kernel<<<2048, TB, 0, stream>>>(x, W1, nullptr, t, N, 0);
        init_self_kernel<<<gN32, TB, 0, stream>>>((const float4*)t, dinv, b1, (float4*)out, N);
        agg_edge_kernel<<<gE32h, TB, 0, stream>>>((const float4*)t, src, dst, dinv, out, E);

        gemm128_kernel<<<2048, TB, 0, stream>>>(out, W2, nullptr, t, N, 1);
        init_self_kernel<<<gN32, TB, 0, stream>>>((const float4*)t, dinv, b2, (float4*)out, N);
        agg_edge_kernel<<<gE32h, TB, 0, stream>>>((const float4*)t, src, dst, dinv, out, E);

        gemm128_kernel<<<2048, TB, 0, stream>>>(out, Wmu, Wls, t, N, 1);
        init_final_kernel<<<gN32, TB, 0, stream>>>((const float4*)t, dinv, bmu, bls, (float4*)out, N);
        agg_edge_final_kernel<<<gE32h, TB, 0, stream>>>((const float4*)t, src, dst, dinv, out, N, E);
    }
}

// Round 5
// 764.674 us; speedup vs baseline: 1.0527x; 1.0527x over previous
//
#include <hip/hip_runtime.h>
#include <hip/hip_bf16.h>

// ---------------- small helpers ----------------
__device__ __forceinline__ float4 f4_fma(float4 a, float s, float4 acc) {
    acc.x = fmaf(a.x, s, acc.x); acc.y = fmaf(a.y, s, acc.y);
    acc.z = fmaf(a.z, s, acc.z); acc.w = fmaf(a.w, s, acc.w);
    return acc;
}
__device__ __forceinline__ float4 f4_add(float4 a, float4 b) {
    return make_float4(a.x + b.x, a.y + b.y, a.z + b.z, a.w + b.w);
}

typedef const __attribute__((address_space(1))) unsigned int* gas_u32;
typedef __attribute__((address_space(3))) unsigned int* las_u32;

__device__ __forceinline__ void gl_lds16(const float* g, float* l) {
    __builtin_amdgcn_global_load_lds((gas_u32)(const void*)g, (las_u32)(void*)l, 16, 0, 0);
}

// ---------------- degree count ----------------
__global__ __launch_bounds__(256) void cnt_count_kernel(const int* __restrict__ dst, int* cnt, int E) {
    int i = blockIdx.x * blockDim.x + threadIdx.x;
    if (i < E) atomicAdd(&cnt[dst[i]], 1);
}

// ---------------- exclusive scan (N ~ 100k) ----------------
#define SCAN_CHUNK 4096  // 256 threads * 16

__global__ __launch_bounds__(256) void scan_reduce_kernel(const int* __restrict__ cnt, int* bsum, int N) {
    __shared__ int sdata[256];
    int base = blockIdx.x * SCAN_CHUNK;
    int s = 0;
    for (int k = 0; k < 16; ++k) {
        int i = base + k * 256 + threadIdx.x;
        if (i < N) s += cnt[i];
    }
    sdata[threadIdx.x] = s;
    __syncthreads();
    for (int off = 128; off > 0; off >>= 1) {
        if (threadIdx.x < off) sdata[threadIdx.x] += sdata[threadIdx.x + off];
        __syncthreads();
    }
    if (threadIdx.x == 0) bsum[blockIdx.x] = sdata[0];
}

__global__ void scan_bsum_kernel(int* bsum, int B, int* rowptr_end, int E) {
    if (threadIdx.x == 0 && blockIdx.x == 0) {
        int run = 0;
        for (int i = 0; i < B; ++i) { int v = bsum[i]; bsum[i] = run; run += v; }
        *rowptr_end = E;  // rowptr[N] = E
    }
}

// also emits dinv (rsqrt(deg)) and cursor (= rowptr copy) to fuse two elementwise passes
__global__ __launch_bounds__(256) void scan_write_kernel(const int* __restrict__ cnt,
                                                         const int* __restrict__ bsum,
                                                         int* rowptr, int* cursor,
                                                         float* dinv, int N) {
    __shared__ int sdata[256];
    int base = blockIdx.x * SCAN_CHUNK;
    int tbase = base + threadIdx.x * 16;
    int loc[16];
    int s = 0;
    for (int k = 0; k < 16; ++k) {
        int i = tbase + k;
        int v = (i < N) ? cnt[i] : 0;
        loc[k] = s; s += v;
    }
    sdata[threadIdx.x] = s;
    __syncthreads();
    for (int off = 1; off < 256; off <<= 1) {
        int v = sdata[threadIdx.x];
        int add = (threadIdx.x >= off) ? sdata[threadIdx.x - off] : 0;
        __syncthreads();
        sdata[threadIdx.x] = v + add;
        __syncthreads();
    }
    int texcl = (threadIdx.x == 0) ? 0 : sdata[threadIdx.x - 1];
    int boff = bsum[blockIdx.x];
    for (int k = 0; k < 16; ++k) {
        int i = tbase + k;
        if (i < N) {
            int rp = boff + texcl + loc[k];
            rowptr[i] = rp;
            cursor[i] = rp;
            dinv[i] = rsqrtf((float)(cnt[i] + 1));
        }
    }
}

// col-only fill (edge weights folded into pre-scaled t' and epilogue dinv[v])
__global__ __launch_bounds__(256) void csr_fill_kernel(const int* __restrict__ src,
                                                       const int* __restrict__ dst,
                                                       int* cursor, int* __restrict__ col,
                                                       int E) {
    int e = blockIdx.x * blockDim.x + threadIdx.x;
    if (e >= E) return;
    int s = src[e], d = dst[e];
    int pos = atomicAdd(&cursor[d], 1);
    col[pos] = s;
}

// ---------------- register-tiled GEMM: t[N][128] = (h[N][128] @ W[128][128]) * dinv[row] ----------------
// 256 threads, tile = 64 rows x 128 cols. Thread: 8 rows x 4 cols acc.
// W read from global (L1/L2-resident, 2KB unique per 4k-step per block);
// h tile double-buffered in LDS (2x32KB) via global_load_lds -> 64KB LDS, 2 blocks/CU.
#define TILE_R 64

__global__ __launch_bounds__(256, 2) void gemm128_tiled(const float* __restrict__ h,
                                                        const float* __restrict__ Wa,
                                                        const float* __restrict__ Wb,
                                                        const float* __restrict__ dinv,
                                                        float* __restrict__ t,
                                                        int N, int ntiles) {
    __shared__ float hl[2][TILE_R * 128];

    const int lane = threadIdx.x & 63;
    const int wav  = threadIdx.x >> 6;   // 0..3
    const int jf4  = threadIdx.x & 31;   // float4 col index
    const int rg   = threadIdx.x >> 5;   // 0..7 (rows rg*8..rg*8+7)

    // per-thread W column pointer (global, cached)
    const float* wptr;
    int wstride;
    if (Wb) { wptr = (jf4 < 16) ? (Wa + jf4 * 4) : (Wb + (jf4 - 16) * 4); wstride = 64; }
    else    { wptr = Wa + jf4 * 4; wstride = 128; }

    auto stage = [&](int buf, long long tile) {
        if (tile >= ntiles) return;
        long long row0 = tile * TILE_R;
        if (row0 + TILE_R <= N) {
            const float* gbase = h + row0 * 128 + (size_t)wav * (16 * 128) + lane * 4;
            float* lbase = &hl[buf][wav * (16 * 128)];
            #pragma unroll
            for (int m = 0; m < 8; ++m)
                gl_lds16(gbase + m * 256, lbase + m * 256);
        } else {
            for (int i = threadIdx.x; i < TILE_R * 32; i += 256) {
                int rl = i >> 5, k4 = i & 31;
                long long row = row0 + rl;
                float4 v = (row < N) ? ((const float4*)h)[row * 32 + k4]
                                     : make_float4(0.f, 0.f, 0.f, 0.f);
                *(float4*)&hl[buf][rl * 128 + k4 * 4] = v;
            }
        }
    };

    long long tile = blockIdx.x;
    stage(0, tile);
    __syncthreads();
    int cur = 0;

    for (; tile < ntiles; tile += gridDim.x) {
        stage(cur ^ 1, tile + gridDim.x);  // prefetch next tile into other buffer

        float4 acc[8];
        #pragma unroll
        for (int rr = 0; rr < 8; ++rr) acc[rr] = make_float4(0.f, 0.f, 0.f, 0.f);

        const float* hb = &hl[cur][rg * 8 * 128];
        #pragma unroll 4
        for (int k = 0; k < 128; k += 4) {
            float4 w0 = *(const float4*)&wptr[(size_t)(k + 0) * wstride];
            float4 w1 = *(const float4*)&wptr[(size_t)(k + 1) * wstride];
            float4 w2 = *(const float4*)&wptr[(size_t)(k + 2) * wstride];
            float4 w3 = *(const float4*)&wptr[(size_t)(k + 3) * wstride];
            #pragma unroll
            for (int rr = 0; rr < 8; ++rr) {
                float4 hv = *(const float4*)&hb[rr * 128 + k];
                acc[rr] = f4_fma(w0, hv.x, acc[rr]);
                acc[rr] = f4_fma(w1, hv.y, acc[rr]);
                acc[rr] = f4_fma(w2, hv.z, acc[rr]);
                acc[rr] = f4_fma(w3, hv.w, acc[rr]);
            }
        }

        long long row0 = tile * TILE_R;
        #pragma unroll
        for (int rr = 0; rr < 8; ++rr) {
            long long row = row0 + rg * 8 + rr;
            if (row < N) {
                float di = dinv[row];
                float4 r = acc[rr];
                r.x *= di; r.y *= di; r.z *= di; r.w *= di;
                ((float4*)t)[row * 32 + jf4] = r;
            }
        }
        __syncthreads();
        cur ^= 1;
    }
}

// ---------------- pull aggregation ----------------
// t' is pre-scaled by dinv[src]; out[v] = dinv[v]*(sum t'[col[e]] + t'[v]) + b ; optional relu
__global__ __launch_bounds__(256) void agg_pull_kernel(const float4* __restrict__ t4,
                                                       const int* __restrict__ rowptr,
                                                       const int* __restrict__ col,
                                                       const float* __restrict__ dinv,
                                                       const float* __restrict__ b,
                                                       float4* __restrict__ out4,
                                                       int N, int relu) {
    int v = blockIdx.x * 8 + (threadIdx.x >> 5);
    int c = threadIdx.x & 31;
    if (v >= N) return;
    int beg = rowptr[v], end = rowptr[v + 1];
    float4 acc0 = t4[(size_t)v * 32 + c];  // self-loop (already dinv[v]-scaled)
    float4 acc1 = make_float4(0.f, 0.f, 0.f, 0.f);
    float4 acc2 = make_float4(0.f, 0.f, 0.f, 0.f);
    float4 acc3 = make_float4(0.f, 0.f, 0.f, 0.f);
    int e = beg;
    for (; e + 7 < end; e += 8) {
        int s0 = col[e],     s1 = col[e + 1], s2 = col[e + 2], s3 = col[e + 3];
        int s4 = col[e + 4], s5 = col[e + 5], s6 = col[e + 6], s7 = col[e + 7];
        float4 v0 = t4[(size_t)s0 * 32 + c];
        float4 v1 = t4[(size_t)s1 * 32 + c];
        float4 v2 = t4[(size_t)s2 * 32 + c];
        float4 v3 = t4[(size_t)s3 * 32 + c];
        float4 v4 = t4[(size_t)s4 * 32 + c];
        float4 v5 = t4[(size_t)s5 * 32 + c];
        float4 v6 = t4[(size_t)s6 * 32 + c];
        float4 v7 = t4[(size_t)s7 * 32 + c];
        acc0 = f4_add(acc0, v0); acc1 = f4_add(acc1, v1);
        acc2 = f4_add(acc2, v2); acc3 = f4_add(acc3, v3);
        acc0 = f4_add(acc0, v4); acc1 = f4_add(acc1, v5);
        acc2 = f4_add(acc2, v6); acc3 = f4_add(acc3, v7);
    }
    for (; e + 3 < end; e += 4) {
        int s0 = col[e], s1 = col[e + 1], s2 = col[e + 2], s3 = col[e + 3];
        acc0 = f4_add(acc0, t4[(size_t)s0 * 32 + c]);
        acc1 = f4_add(acc1, t4[(size_t)s1 * 32 + c]);
        acc2 = f4_add(acc2, t4[(size_t)s2 * 32 + c]);
        acc3 = f4_add(acc3, t4[(size_t)s3 * 32 + c]);
    }
    for (; e < end; ++e) acc0 = f4_add(acc0, t4[(size_t)col[e] * 32 + c]);
    float di = dinv[v];
    float4 s = f4_add(f4_add(acc0, acc1), f4_add(acc2, acc3));
    float4 bb = ((const float4*)b)[c];
    float4 r = f4_fma(s, di, bb);
    if (relu) {
        r.x = fmaxf(r.x, 0.f); r.y = fmaxf(r.y, 0.f);
        r.z = fmaxf(r.z, 0.f); r.w = fmaxf(r.w, 0.f);
    }
    out4[(size_t)v * 32 + c] = r;
}

// final layer: cols 0..63 -> mu, 64..127 -> logstd (split output)
__global__ __launch_bounds__(256) void agg_pull_final_kernel(const float4* __restrict__ t4,
                                                             const int* __restrict__ rowptr,
                                                             const int* __restrict__ col,
                                                             const float* __restrict__ dinv,
                                                             const float* __restrict__ bmu,
                                                             const float* __restrict__ bls,
                                                             float4* __restrict__ out4,
                                                             int N) {
    int v = blockIdx.x * 8 + (threadIdx.x >> 5);
    int c = threadIdx.x & 31;
    if (v >= N) return;
    int half = c >> 4, cc = c & 15;
    int beg = rowptr[v], end = rowptr[v + 1];
    float4 acc0 = t4[(size_t)v * 32 + c];
    float4 acc1 = make_float4(0.f, 0.f, 0.f, 0.f);
    float4 acc2 = make_float4(0.f, 0.f, 0.f, 0.f);
    float4 acc3 = make_float4(0.f, 0.f, 0.f, 0.f);
    int e = beg;
    for (; e + 7 < end; e += 8) {
        int s0 = col[e],     s1 = col[e + 1], s2 = col[e + 2], s3 = col[e + 3];
        int s4 = col[e + 4], s5 = col[e + 5], s6 = col[e + 6], s7 = col[e + 7];
        float4 v0 = t4[(size_t)s0 * 32 + c];
        float4 v1 = t4[(size_t)s1 * 32 + c];
        float4 v2 = t4[(size_t)s2 * 32 + c];
        float4 v3 = t4[(size_t)s3 * 32 + c];
        float4 v4 = t4[(size_t)s4 * 32 + c];
        float4 v5 = t4[(size_t)s5 * 32 + c];
        float4 v6 = t4[(size_t)s6 * 32 + c];
        float4 v7 = t4[(size_t)s7 * 32 + c];
        acc0 = f4_add(acc0, v0); acc1 = f4_add(acc1, v1);
        acc2 = f4_add(acc2, v2); acc3 = f4_add(acc3, v3);
        acc0 = f4_add(acc0, v4); acc1 = f4_add(acc1, v5);
        acc2 = f4_add(acc2, v6); acc3 = f4_add(acc3, v7);
    }
    for (; e + 3 < end; e += 4) {
        int s0 = col[e], s1 = col[e + 1], s2 = col[e + 2], s3 = col[e + 3];
        acc0 = f4_add(acc0, t4[(size_t)s0 * 32 + c]);
        acc1 = f4_add(acc1, t4[(size_t)s1 * 32 + c]);
        acc2 = f4_add(acc2, t4[(size_t)s2 * 32 + c]);
        acc3 = f4_add(acc3, t4[(size_t)s3 * 32 + c]);
    }
    for (; e < end; ++e) acc0 = f4_add(acc0, t4[(size_t)col[e] * 32 + c]);
    float di = dinv[v];
    float4 s = f4_add(f4_add(acc0, acc1), f4_add(acc2, acc3));
    float4 bb = half ? ((const float4*)bls)[cc] : ((const float4*)bmu)[cc];
    out4[(size_t)half * N * 16 + (size_t)v * 16 + cc] = f4_fma(s, di, bb);
}

// ---------------- fallback (atomic scatter) kernels ----------------
__global__ __launch_bounds__(256) void deg_init_kernel(float* deg, int N) {
    int i = blockIdx.x * blockDim.x + threadIdx.x;
    if (i < N) deg[i] = 1.0f;
}
__global__ __launch_bounds__(256) void deg_count_kernel(const int* __restrict__ dst, float* deg, int E) {
    int i = blockIdx.x * blockDim.x + threadIdx.x;
    if (i < E) unsafeAtomicAdd(&deg[dst[i]], 1.0f);
}
__global__ __launch_bounds__(256) void deg_rsqrt_kernel(float* deg, int N) {
    int i = blockIdx.x * blockDim.x + threadIdx.x;
    if (i < N) deg[i] = rsqrtf(deg[i]);
}
__global__ __launch_bounds__(256) void gemm128_kernel(const float* __restrict__ h,
                                                      const float* __restrict__ Wa,
                                                      const float* __restrict__ Wb,
                                                      float* __restrict__ t,
                                                      int N, int relu) {
    __shared__ float Wl[128 * 128];
    __shared__ float hl[2][128];
    for (int i = threadIdx.x; i < 128 * 128; i += 256) {
        int k = i >> 7, j = i & 127;
        float w;
        if (Wb) w = (j < 64) ? Wa[k * 64 + j] : Wb[k * 64 + (j - 64)];
        else    w = Wa[i];
        Wl[i] = w;
    }
    __syncthreads();
    int col = threadIdx.x & 127;
    int r   = threadIdx.x >> 7;
    for (long long pair = blockIdx.x; pair * 2 < N; pair += gridDim.x) {
        int row0 = (int)(pair * 2);
        {
            int rr = threadIdx.x >> 7, k = threadIdx.x & 127;
            int row = row0 + rr;
            float v = (row < N) ? h[(size_t)row * 128 + k] : 0.0f;
            if (relu) v = fmaxf(v, 0.0f);
            hl[rr][k] = v;
        }
        __syncthreads();
        float acc = 0.0f;
        #pragma unroll
        for (int k = 0; k < 128; k += 4) {
            float4 hv = *(const float4*)&hl[r][k];
            acc += hv.x * Wl[(k + 0) * 128 + col];
            acc += hv.y * Wl[(k + 1) * 128 + col];
            acc += hv.z * Wl[(k + 2) * 128 + col];
            acc += hv.w * Wl[(k + 3) * 128 + col];
        }
        int row = row0 + r;
        if (row < N) t[(size_t)row * 128 + col] = acc;
        __syncthreads();
    }
}
__global__ __launch_bounds__(256) void init_self_kernel(const float4* __restrict__ t4,
                                                        const float* __restrict__ dinv,
                                                        const float* __restrict__ b,
                                                        float4* __restrict__ out, int N) {
    int idx = blockIdx.x * blockDim.x + threadIdx.x;
    int v = idx >> 5, c = idx & 31;
    if (v >= N) return;
    float di = dinv[v];
    float s = di * di;
    float4 x = t4[(size_t)v * 32 + c];
    float4 bb = ((const float4*)b)[c];
    out[(size_t)v * 32 + c] = make_float4(fmaf(x.x, s, bb.x), fmaf(x.y, s, bb.y),
                                          fmaf(x.z, s, bb.z), fmaf(x.w, s, bb.w));
}
__global__ __launch_bounds__(256) void init_final_kernel(const float4* __restrict__ t4,
                                                         const float* __restrict__ dinv,
                                                         const float* __restrict__ bmu,
                                                         const float* __restrict__ bls,
                                                         float4* __restrict__ out4, int N) {
    int idx = blockIdx.x * blockDim.x + threadIdx.x;
    int v = idx >> 5, c = idx & 31;
    if (v >= N) return;
    int half = c >> 4, cc = c & 15;
    float di = dinv[v];
    float s = di * di;
    float4 x = t4[(size_t)v * 32 + c];
    float4 bb = half ? ((const float4*)bls)[cc] : ((const float4*)bmu)[cc];
    out4[(size_t)half * N * 16 + (size_t)v * 16 + cc] =
        make_float4(fmaf(x.x, s, bb.x), fmaf(x.y, s, bb.y),
                    fmaf(x.z, s, bb.z), fmaf(x.w, s, bb.w));
}
__global__ __launch_bounds__(256) void agg_edge_kernel(const float4* __restrict__ t4,
                                                       const int* __restrict__ src,
                                                       const int* __restrict__ dst,
                                                       const float* __restrict__ dinv,
                                                       float* __restrict__ out, int E) {
    int idx = blockIdx.x * blockDim.x + threadIdx.x;
    int e = idx >> 5, c = idx & 31;
    if (e >= E) return;
    int s = src[e], d = dst[e];
    float w = dinv[s] * dinv[d];
    float4 v = t4[(size_t)s * 32 + c];
    float* o = out + (size_t)d * 128 + c * 4;
    unsafeAtomicAdd(o + 0, v.x * w);
    unsafeAtomicAdd(o + 1, v.y * w);
    unsafeAtomicAdd(o + 2, v.z * w);
    unsafeAtomicAdd(o + 3, v.w * w);
}
__global__ __launch_bounds__(256) void agg_edge_final_kernel(const float4* __restrict__ t4,
                                                             const int* __restrict__ src,
                                                             const int* __restrict__ dst,
                                                             const float* __restrict__ dinv,
                                                             float* __restrict__ out, int N, int E) {
    int idx = blockIdx.x * blockDim.x + threadIdx.x;
    int e = idx >> 5, c = idx & 31;
    if (e >= E) return;
    int s = src[e], d = dst[e];
    int half = c >> 4, cc = c & 15;
    float w = dinv[s] * dinv[d];
    float4 v = t4[(size_t)s * 32 + c];
    float* o = out + (size_t)half * N * 64 + (size_t)d * 64 + cc * 4;
    unsafeAtomicAdd(o + 0, v.x * w);
    unsafeAtomicAdd(o + 1, v.y * w);
    unsafeAtomicAdd(o + 2, v.z * w);
    unsafeAtomicAdd(o + 3, v.w * w);
}

// ---------------- launch ----------------
extern "C" void kernel_launch(void* const* d_in, const int* in_sizes, int n_in,
                              void* d_out, int out_size, void* d_ws, size_t ws_size,
                              hipStream_t stream) {
    const float* x   = (const float*)d_in[0];
    const int*   ei  = (const int*)d_in[1];
    const float* W1  = (const float*)d_in[2];
    const float* b1  = (const float*)d_in[3];
    const float* W2  = (const float*)d_in[4];
    const float* b2  = (const float*)d_in[5];
    const float* Wmu = (const float*)d_in[6];
    const float* bmu = (const float*)d_in[7];
    const float* Wls = (const float*)d_in[8];
    const float* bls = (const float*)d_in[9];

    const int N = in_sizes[0] / 128;
    const int E = in_sizes[1] / 2;
    const int* src = ei;
    const int* dst = ei + E;

    float* out = (float*)d_out;  // reused as h1/h2 buffer

    auto align256 = [](size_t o) { return (o + 255) & ~(size_t)255; };
    const int B1 = (N + SCAN_CHUNK - 1) / SCAN_CHUNK;

    size_t off = 0;
    size_t o_dinv   = off; off = align256(off + (size_t)N * 4);
    size_t o_t      = off; off = align256(off + (size_t)N * 128 * 4);
    size_t o_rowptr = off; off = align256(off + (size_t)(N + 1) * 4);
    size_t o_cursor = off; off = align256(off + (size_t)N * 4);       // also cnt
    size_t o_bsum   = off; off = align256(off + (size_t)B1 * 4);
    size_t o_col    = off; off = align256(off + (size_t)E * 4);
    size_t need = off;

    float* dinv = (float*)((char*)d_ws + o_dinv);
    float* t    = (float*)((char*)d_ws + o_t);

    const int TB = 256;
    int gN = (N + TB - 1) / TB;
    int gE = (E + TB - 1) / TB;
    int ntiles = (N + TILE_R - 1) / TILE_R;

    if (ws_size >= need) {
        int* rowptr = (int*)((char*)d_ws + o_rowptr);
        int* cursor = (int*)((char*)d_ws + o_cursor);
        int* bsum   = (int*)((char*)d_ws + o_bsum);
        int* col    = (int*)((char*)d_ws + o_col);

        // CSR build (col-only; weights folded into t' pre-scale + epilogue)
        hipMemsetAsync(cursor, 0, (size_t)N * 4, stream);
        cnt_count_kernel<<<gE, TB, 0, stream>>>(dst, cursor, E);
        scan_reduce_kernel<<<B1, TB, 0, stream>>>(cursor, bsum, N);
        scan_bsum_kernel<<<1, 64, 0, stream>>>(bsum, B1, rowptr + N, E);
        scan_write_kernel<<<B1, TB, 0, stream>>>(cursor, bsum, rowptr, cursor, dinv, N);
        csr_fill_kernel<<<gE, TB, 0, stream>>>(src, dst, cursor, col, E);

        int gPull = (N + 7) / 8;
        // layer 1
        gemm128_tiled<<<512, TB, 0, stream>>>(x, W1, nullptr, dinv, t, N, ntiles);
        agg_pull_kernel<<<gPull, TB, 0, stream>>>((const float4*)t, rowptr, col, dinv, b1, (float4*)out, N, 1);
        // layer 2
        gemm128_tiled<<<512, TB, 0, stream>>>(out, W2, nullptr, dinv, t, N, ntiles);
        agg_pull_kernel<<<gPull, TB, 0, stream>>>((const float4*)t, rowptr, col, dinv, b2, (float4*)out, N, 1);
        // layer 3+4 fused
        gemm128_tiled<<<512, TB, 0, stream>>>(out, Wmu, Wls, dinv, t, N, ntiles);
        agg_pull_final_kernel<<<gPull, TB, 0, stream>>>((const float4*)t, rowptr, col, dinv, bmu, bls, (float4*)out, N);
    } else {
        // fallback: atomic scatter path
        int gN32  = (N * 32 + TB - 1) / TB;
        int gE32h = (int)(((long long)E * 32 + TB - 1) / TB);
        deg_init_kernel<<<gN, TB, 0, stream>>>(dinv, N);
        deg_count_kernel<<<gE, TB, 0, stream>>>(dst, dinv, E);
        deg_rsqrt_kernel<<<gN, TB, 0, stream>>>(dinv, N);

        gemm128_kernel<<<2048, TB, 0, stream>>>(x, W1, nullptr, t, N, 0);
        init_self_kernel<<<gN32, TB, 0, stream>>>((const float4*)t, dinv, b1, (float4*)out, N);
        agg_edge_kernel<<<gE32h, TB, 0, stream>>>((const float4*)t, src, dst, dinv, out, E);

        gemm128_kernel<<<2048, TB, 0, stream>>>(out, W2, nullptr, t, N, 1);
        init_self_kernel<<<gN32, TB, 0, stream>>>((const float4*)t, dinv, b2, (float4*)out, N);
        agg_edge_kernel<<<gE32h, TB, 0, stream>>>((const float4*)t, src, dst, dinv, out, E);

        gemm128_kernel<<<2048, TB, 0, stream>>>(out, Wmu, Wls, t, N, 1);
        init_final_kernel<<<gN32, TB, 0, stream>>>((const float4*)t, dinv, bmu, bls, (float4*)out, N);
        agg_edge_final_kernel<<<gE32h, TB, 0, stream>>>((const float4*)t, src, dst, dinv, out, N, E);
    }
}

// Round 6
// 752.135 us; speedup vs baseline: 1.0703x; 1.0167x over previous
//
#include <hip/hip_runtime.h>
#include <hip/hip_bf16.h>

// ---------------- small helpers ----------------
__device__ __forceinline__ float4 f4_fma(float4 a, float s, float4 acc) {
    acc.x = fmaf(a.x, s, acc.x); acc.y = fmaf(a.y, s, acc.y);
    acc.z = fmaf(a.z, s, acc.z); acc.w = fmaf(a.w, s, acc.w);
    return acc;
}
__device__ __forceinline__ float4 f4_add(float4 a, float4 b) {
    return make_float4(a.x + b.x, a.y + b.y, a.z + b.z, a.w + b.w);
}

typedef const __attribute__((address_space(1))) unsigned int* gas_u32;
typedef __attribute__((address_space(3))) unsigned int* las_u32;

__device__ __forceinline__ void gl_lds16(const float* g, float* l) {
    __builtin_amdgcn_global_load_lds((gas_u32)(const void*)g, (las_u32)(void*)l, 16, 0, 0);
}

// ---------------- degree count ----------------
__global__ __launch_bounds__(256) void cnt_count_kernel(const int* __restrict__ dst, int* cnt, int E) {
    int i = blockIdx.x * blockDim.x + threadIdx.x;
    if (i < E) atomicAdd(&cnt[dst[i]], 1);
}

// ---------------- exclusive scan (N ~ 100k) ----------------
#define SCAN_CHUNK 4096  // 256 threads * 16

__global__ __launch_bounds__(256) void scan_reduce_kernel(const int* __restrict__ cnt, int* bsum, int N) {
    __shared__ int sdata[256];
    int base = blockIdx.x * SCAN_CHUNK;
    int s = 0;
    for (int k = 0; k < 16; ++k) {
        int i = base + k * 256 + threadIdx.x;
        if (i < N) s += cnt[i];
    }
    sdata[threadIdx.x] = s;
    __syncthreads();
    for (int off = 128; off > 0; off >>= 1) {
        if (threadIdx.x < off) sdata[threadIdx.x] += sdata[threadIdx.x + off];
        __syncthreads();
    }
    if (threadIdx.x == 0) bsum[blockIdx.x] = sdata[0];
}

__global__ void scan_bsum_kernel(int* bsum, int B, int* rowptr_end, int E) {
    if (threadIdx.x == 0 && blockIdx.x == 0) {
        int run = 0;
        for (int i = 0; i < B; ++i) { int v = bsum[i]; bsum[i] = run; run += v; }
        *rowptr_end = E;  // rowptr[N] = E
    }
}

// also emits dinv (rsqrt(deg)) and cursor (= rowptr copy)
__global__ __launch_bounds__(256) void scan_write_kernel(const int* __restrict__ cnt,
                                                         const int* __restrict__ bsum,
                                                         int* rowptr, int* cursor,
                                                         float* dinv, int N) {
    __shared__ int sdata[256];
    int base = blockIdx.x * SCAN_CHUNK;
    int tbase = base + threadIdx.x * 16;
    int loc[16];
    int s = 0;
    for (int k = 0; k < 16; ++k) {
        int i = tbase + k;
        int v = (i < N) ? cnt[i] : 0;
        loc[k] = s; s += v;
    }
    sdata[threadIdx.x] = s;
    __syncthreads();
    for (int off = 1; off < 256; off <<= 1) {
        int v = sdata[threadIdx.x];
        int add = (threadIdx.x >= off) ? sdata[threadIdx.x - off] : 0;
        __syncthreads();
        sdata[threadIdx.x] = v + add;
        __syncthreads();
    }
    int texcl = (threadIdx.x == 0) ? 0 : sdata[threadIdx.x - 1];
    int boff = bsum[blockIdx.x];
    for (int k = 0; k < 16; ++k) {
        int i = tbase + k;
        if (i < N) {
            int rp = boff + texcl + loc[k];
            rowptr[i] = rp;
            cursor[i] = rp;
            dinv[i] = rsqrtf((float)(cnt[i] + 1));
        }
    }
}

// col-only fill
__global__ __launch_bounds__(256) void csr_fill_kernel(const int* __restrict__ src,
                                                       const int* __restrict__ dst,
                                                       int* cursor, int* __restrict__ col,
                                                       int E) {
    int e = blockIdx.x * blockDim.x + threadIdx.x;
    if (e >= E) return;
    int s = src[e], d = dst[e];
    int pos = atomicAdd(&cursor[d], 1);
    col[pos] = s;
}

// ---------------- register-tiled GEMM: t[N][128] = (h[N][128] @ W) * dinv[row] ----------------
#define TILE_R 64

__global__ __launch_bounds__(256, 2) void gemm128_tiled(const float* __restrict__ h,
                                                        const float* __restrict__ Wa,
                                                        const float* __restrict__ Wb,
                                                        const float* __restrict__ dinv,
                                                        float* __restrict__ t,
                                                        int N, int ntiles) {
    __shared__ float hl[2][TILE_R * 128];

    const int lane = threadIdx.x & 63;
    const int wav  = threadIdx.x >> 6;
    const int jf4  = threadIdx.x & 31;
    const int rg   = threadIdx.x >> 5;

    const float* wptr;
    int wstride;
    if (Wb) { wptr = (jf4 < 16) ? (Wa + jf4 * 4) : (Wb + (jf4 - 16) * 4); wstride = 64; }
    else    { wptr = Wa + jf4 * 4; wstride = 128; }

    auto stage = [&](int buf, long long tile) {
        if (tile >= ntiles) return;
        long long row0 = tile * TILE_R;
        if (row0 + TILE_R <= N) {
            const float* gbase = h + row0 * 128 + (size_t)wav * (16 * 128) + lane * 4;
            float* lbase = &hl[buf][wav * (16 * 128)];
            #pragma unroll
            for (int m = 0; m < 8; ++m)
                gl_lds16(gbase + m * 256, lbase + m * 256);
        } else {
            for (int i = threadIdx.x; i < TILE_R * 32; i += 256) {
                int rl = i >> 5, k4 = i & 31;
                long long row = row0 + rl;
                float4 v = (row < N) ? ((const float4*)h)[row * 32 + k4]
                                     : make_float4(0.f, 0.f, 0.f, 0.f);
                *(float4*)&hl[buf][rl * 128 + k4 * 4] = v;
            }
        }
    };

    long long tile = blockIdx.x;
    stage(0, tile);
    __syncthreads();
    int cur = 0;

    for (; tile < ntiles; tile += gridDim.x) {
        stage(cur ^ 1, tile + gridDim.x);

        float4 acc[8];
        #pragma unroll
        for (int rr = 0; rr < 8; ++rr) acc[rr] = make_float4(0.f, 0.f, 0.f, 0.f);

        const float* hb = &hl[cur][rg * 8 * 128];
        #pragma unroll 4
        for (int k = 0; k < 128; k += 4) {
            float4 w0 = *(const float4*)&wptr[(size_t)(k + 0) * wstride];
            float4 w1 = *(const float4*)&wptr[(size_t)(k + 1) * wstride];
            float4 w2 = *(const float4*)&wptr[(size_t)(k + 2) * wstride];
            float4 w3 = *(const float4*)&wptr[(size_t)(k + 3) * wstride];
            #pragma unroll
            for (int rr = 0; rr < 8; ++rr) {
                float4 hv = *(const float4*)&hb[rr * 128 + k];
                acc[rr] = f4_fma(w0, hv.x, acc[rr]);
                acc[rr] = f4_fma(w1, hv.y, acc[rr]);
                acc[rr] = f4_fma(w2, hv.z, acc[rr]);
                acc[rr] = f4_fma(w3, hv.w, acc[rr]);
            }
        }

        long long row0 = tile * TILE_R;
        #pragma unroll
        for (int rr = 0; rr < 8; ++rr) {
            long long row = row0 + rg * 8 + rr;
            if (row < N) {
                float di = dinv[row];
                float4 r = acc[rr];
                r.x *= di; r.y *= di; r.z *= di; r.w *= di;
                ((float4*)t)[row * 32 + jf4] = r;
            }
        }
        __syncthreads();
        cur ^= 1;
    }
}

// ---------------- fused agg(layer k) + gemm(layer k+1) ----------------
// Block owns 64 dst rows. Phase A: pull-aggregate + relu into LDS.
// Phase B: register-tiled GEMM from LDS; t_out = (h @ [Wa|Wb]) * dinv[row].
__global__ __launch_bounds__(256) void fused_agg_gemm(const float4* __restrict__ t4,
                                                      const int* __restrict__ rowptr,
                                                      const int* __restrict__ col,
                                                      const float* __restrict__ dinv,
                                                      const float* __restrict__ bvec,
                                                      const float* __restrict__ Wa,
                                                      const float* __restrict__ Wb,
                                                      float* __restrict__ tout,
                                                      int N) {
    __shared__ float hl[TILE_R * 128];  // 32 KB

    const int grp = threadIdx.x >> 5;   // 0..7
    const int c   = threadIdx.x & 31;   // float4 col
    const long long row0 = (long long)blockIdx.x * TILE_R;

    // Phase A: each 32-lane group aggregates 8 rows into LDS (with relu)
    float4 bb = ((const float4*)bvec)[c];
    #pragma unroll 1
    for (int r = 0; r < 8; ++r) {
        long long v = row0 + grp * 8 + r;
        float4 res;
        if (v < N) {
            int beg = rowptr[v], end = rowptr[v + 1];
            float4 acc0 = t4[(size_t)v * 32 + c];  // self-loop (pre-scaled)
            float4 acc1 = make_float4(0.f, 0.f, 0.f, 0.f);
            float4 acc2 = make_float4(0.f, 0.f, 0.f, 0.f);
            float4 acc3 = make_float4(0.f, 0.f, 0.f, 0.f);
            int e = beg;
            for (; e + 7 < end; e += 8) {
                int s0 = col[e],     s1 = col[e + 1], s2 = col[e + 2], s3 = col[e + 3];
                int s4 = col[e + 4], s5 = col[e + 5], s6 = col[e + 6], s7 = col[e + 7];
                float4 v0 = t4[(size_t)s0 * 32 + c];
                float4 v1 = t4[(size_t)s1 * 32 + c];
                float4 v2 = t4[(size_t)s2 * 32 + c];
                float4 v3 = t4[(size_t)s3 * 32 + c];
                float4 v4 = t4[(size_t)s4 * 32 + c];
                float4 v5 = t4[(size_t)s5 * 32 + c];
                float4 v6 = t4[(size_t)s6 * 32 + c];
                float4 v7 = t4[(size_t)s7 * 32 + c];
                acc0 = f4_add(acc0, v0); acc1 = f4_add(acc1, v1);
                acc2 = f4_add(acc2, v2); acc3 = f4_add(acc3, v3);
                acc0 = f4_add(acc0, v4); acc1 = f4_add(acc1, v5);
                acc2 = f4_add(acc2, v6); acc3 = f4_add(acc3, v7);
            }
            for (; e + 3 < end; e += 4) {
                int s0 = col[e], s1 = col[e + 1], s2 = col[e + 2], s3 = col[e + 3];
                acc0 = f4_add(acc0, t4[(size_t)s0 * 32 + c]);
                acc1 = f4_add(acc1, t4[(size_t)s1 * 32 + c]);
                acc2 = f4_add(acc2, t4[(size_t)s2 * 32 + c]);
                acc3 = f4_add(acc3, t4[(size_t)s3 * 32 + c]);
            }
            for (; e < end; ++e) acc0 = f4_add(acc0, t4[(size_t)col[e] * 32 + c]);
            float di = dinv[v];
            float4 s = f4_add(f4_add(acc0, acc1), f4_add(acc2, acc3));
            res = f4_fma(s, di, bb);
            res.x = fmaxf(res.x, 0.f); res.y = fmaxf(res.y, 0.f);
            res.z = fmaxf(res.z, 0.f); res.w = fmaxf(res.w, 0.f);
        } else {
            res = make_float4(0.f, 0.f, 0.f, 0.f);
        }
        *(float4*)&hl[(grp * 8 + r) * 128 + c * 4] = res;
    }
    __syncthreads();

    // Phase B: GEMM from LDS (thread: 8 rows x 4 cols)
    const int jf4 = c;
    const int rg  = grp;
    const float* wptr;
    int wstride;
    if (Wb) { wptr = (jf4 < 16) ? (Wa + jf4 * 4) : (Wb + (jf4 - 16) * 4); wstride = 64; }
    else    { wptr = Wa + jf4 * 4; wstride = 128; }

    float4 acc[8];
    #pragma unroll
    for (int rr = 0; rr < 8; ++rr) acc[rr] = make_float4(0.f, 0.f, 0.f, 0.f);

    const float* hb = &hl[rg * 8 * 128];
    #pragma unroll 4
    for (int k = 0; k < 128; k += 4) {
        float4 w0 = *(const float4*)&wptr[(size_t)(k + 0) * wstride];
        float4 w1 = *(const float4*)&wptr[(size_t)(k + 1) * wstride];
        float4 w2 = *(const float4*)&wptr[(size_t)(k + 2) * wstride];
        float4 w3 = *(const float4*)&wptr[(size_t)(k + 3) * wstride];
        #pragma unroll
        for (int rr = 0; rr < 8; ++rr) {
            float4 hv = *(const float4*)&hb[rr * 128 + k];
            acc[rr] = f4_fma(w0, hv.x, acc[rr]);
            acc[rr] = f4_fma(w1, hv.y, acc[rr]);
            acc[rr] = f4_fma(w2, hv.z, acc[rr]);
            acc[rr] = f4_fma(w3, hv.w, acc[rr]);
        }
    }

    #pragma unroll
    for (int rr = 0; rr < 8; ++rr) {
        long long row = row0 + rg * 8 + rr;
        if (row < N) {
            float di = dinv[row];
            float4 r = acc[rr];
            r.x *= di; r.y *= di; r.z *= di; r.w *= di;
            ((float4*)tout)[row * 32 + jf4] = r;
        }
    }
}

// final layer: cols 0..63 -> mu, 64..127 -> logstd (split output)
__global__ __launch_bounds__(256) void agg_pull_final_kernel(const float4* __restrict__ t4,
                                                             const int* __restrict__ rowptr,
                                                             const int* __restrict__ col,
                                                             const float* __restrict__ dinv,
                                                             const float* __restrict__ bmu,
                                                             const float* __restrict__ bls,
                                                             float4* __restrict__ out4,
                                                             int N) {
    int v = blockIdx.x * 8 + (threadIdx.x >> 5);
    int c = threadIdx.x & 31;
    if (v >= N) return;
    int half = c >> 4, cc = c & 15;
    int beg = rowptr[v], end = rowptr[v + 1];
    float4 acc0 = t4[(size_t)v * 32 + c];
    float4 acc1 = make_float4(0.f, 0.f, 0.f, 0.f);
    float4 acc2 = make_float4(0.f, 0.f, 0.f, 0.f);
    float4 acc3 = make_float4(0.f, 0.f, 0.f, 0.f);
    int e = beg;
    for (; e + 7 < end; e += 8) {
        int s0 = col[e],     s1 = col[e + 1], s2 = col[e + 2], s3 = col[e + 3];
        int s4 = col[e + 4], s5 = col[e + 5], s6 = col[e + 6], s7 = col[e + 7];
        float4 v0 = t4[(size_t)s0 * 32 + c];
        float4 v1 = t4[(size_t)s1 * 32 + c];
        float4 v2 = t4[(size_t)s2 * 32 + c];
        float4 v3 = t4[(size_t)s3 * 32 + c];
        float4 v4 = t4[(size_t)s4 * 32 + c];
        float4 v5 = t4[(size_t)s5 * 32 + c];
        float4 v6 = t4[(size_t)s6 * 32 + c];
        float4 v7 = t4[(size_t)s7 * 32 + c];
        acc0 = f4_add(acc0, v0); acc1 = f4_add(acc1, v1);
        acc2 = f4_add(acc2, v2); acc3 = f4_add(acc3, v3);
        acc0 = f4_add(acc0, v4); acc1 = f4_add(acc1, v5);
        acc2 = f4_add(acc2, v6); acc3 = f4_add(acc3, v7);
    }
    for (; e + 3 < end; e += 4) {
        int s0 = col[e], s1 = col[e + 1], s2 = col[e + 2], s3 = col[e + 3];
        acc0 = f4_add(acc0, t4[(size_t)s0 * 32 + c]);
        acc1 = f4_add(acc1, t4[(size_t)s1 * 32 + c]);
        acc2 = f4_add(acc2, t4[(size_t)s2 * 32 + c]);
        acc3 = f4_add(acc3, t4[(size_t)s3 * 32 + c]);
    }
    for (; e < end; ++e) acc0 = f4_add(acc0, t4[(size_t)col[e] * 32 + c]);
    float di = dinv[v];
    float4 s = f4_add(f4_add(acc0, acc1), f4_add(acc2, acc3));
    float4 bb = half ? ((const float4*)bls)[cc] : ((const float4*)bmu)[cc];
    out4[(size_t)half * N * 16 + (size_t)v * 16 + cc] = f4_fma(s, di, bb);
}

// ---------------- fallback (atomic scatter) kernels ----------------
__global__ __launch_bounds__(256) void deg_init_kernel(float* deg, int N) {
    int i = blockIdx.x * blockDim.x + threadIdx.x;
    if (i < N) deg[i] = 1.0f;
}
__global__ __launch_bounds__(256) void deg_count_kernel(const int* __restrict__ dst, float* deg, int E) {
    int i = blockIdx.x * blockDim.x + threadIdx.x;
    if (i < E) unsafeAtomicAdd(&deg[dst[i]], 1.0f);
}
__global__ __launch_bounds__(256) void deg_rsqrt_kernel(float* deg, int N) {
    int i = blockIdx.x * blockDim.x + threadIdx.x;
    if (i < N) deg[i] = rsqrtf(deg[i]);
}
__global__ __launch_bounds__(256) void gemm128_kernel(const float* __restrict__ h,
                                                      const float* __restrict__ Wa,
                                                      const float* __restrict__ Wb,
                                                      float* __restrict__ t,
                                                      int N, int relu) {
    __shared__ float Wl[128 * 128];
    __shared__ float hl[2][128];
    for (int i = threadIdx.x; i < 128 * 128; i += 256) {
        int k = i >> 7, j = i & 127;
        float w;
        if (Wb) w = (j < 64) ? Wa[k * 64 + j] : Wb[k * 64 + (j - 64)];
        else    w = Wa[i];
        Wl[i] = w;
    }
    __syncthreads();
    int col = threadIdx.x & 127;
    int r   = threadIdx.x >> 7;
    for (long long pair = blockIdx.x; pair * 2 < N; pair += gridDim.x) {
        int row0 = (int)(pair * 2);
        {
            int rr = threadIdx.x >> 7, k = threadIdx.x & 127;
            int row = row0 + rr;
            float v = (row < N) ? h[(size_t)row * 128 + k] : 0.0f;
            if (relu) v = fmaxf(v, 0.0f);
            hl[rr][k] = v;
        }
        __syncthreads();
        float acc = 0.0f;
        #pragma unroll
        for (int k = 0; k < 128; k += 4) {
            float4 hv = *(const float4*)&hl[r][k];
            acc += hv.x * Wl[(k + 0) * 128 + col];
            acc += hv.y * Wl[(k + 1) * 128 + col];
            acc += hv.z * Wl[(k + 2) * 128 + col];
            acc += hv.w * Wl[(k + 3) * 128 + col];
        }
        int row = row0 + r;
        if (row < N) t[(size_t)row * 128 + col] = acc;
        __syncthreads();
    }
}
__global__ __launch_bounds__(256) void init_self_kernel(const float4* __restrict__ t4,
                                                        const float* __restrict__ dinv,
                                                        const float* __restrict__ b,
                                                        float4* __restrict__ out, int N) {
    int idx = blockIdx.x * blockDim.x + threadIdx.x;
    int v = idx >> 5, c = idx & 31;
    if (v >= N) return;
    float di = dinv[v];
    float s = di * di;
    float4 x = t4[(size_t)v * 32 + c];
    float4 bb = ((const float4*)b)[c];
    out[(size_t)v * 32 + c] = make_float4(fmaf(x.x, s, bb.x), fmaf(x.y, s, bb.y),
                                          fmaf(x.z, s, bb.z), fmaf(x.w, s, bb.w));
}
__global__ __launch_bounds__(256) void init_final_kernel(const float4* __restrict__ t4,
                                                         const float* __restrict__ dinv,
                                                         const float* __restrict__ bmu,
                                                         const float* __restrict__ bls,
                                                         float4* __restrict__ out4, int N) {
    int idx = blockIdx.x * blockDim.x + threadIdx.x;
    int v = idx >> 5, c = idx & 31;
    if (v >= N) return;
    int half = c >> 4, cc = c & 15;
    float di = dinv[v];
    float s = di * di;
    float4 x = t4[(size_t)v * 32 + c];
    float4 bb = half ? ((const float4*)bls)[cc] : ((const float4*)bmu)[cc];
    out4[(size_t)half * N * 16 + (size_t)v * 16 + cc] =
        make_float4(fmaf(x.x, s, bb.x), fmaf(x.y, s, bb.y),
                    fmaf(x.z, s, bb.z), fmaf(x.w, s, bb.w));
}
__global__ __launch_bounds__(256) void agg_edge_kernel(const float4* __restrict__ t4,
                                                       const int* __restrict__ src,
                                                       const int* __restrict__ dst,
                                                       const float* __restrict__ dinv,
                                                       float* __restrict__ out, int E) {
    int idx = blockIdx.x * blockDim.x + threadIdx.x;
    int e = idx >> 5, c = idx & 31;
    if (e >= E) return;
    int s = src[e], d = dst[e];
    float w = dinv[s] * dinv[d];
    float4 v = t4[(size_t)s * 32 + c];
    float* o = out + (size_t)d * 128 + c * 4;
    unsafeAtomicAdd(o + 0, v.x * w);
    unsafeAtomicAdd(o + 1, v.y * w);
    unsafeAtomicAdd(o + 2, v.z * w);
    unsafeAtomicAdd(o + 3, v.w * w);
}
__global__ __launch_bounds__(256) void agg_edge_final_kernel(const float4* __restrict__ t4,
                                                             const int* __restrict__ src,
                                                             const int* __restrict__ dst,
                                                             const float* __restrict__ dinv,
                                                             float* __restrict__ out, int N, int E) {
    int idx = blockIdx.x * blockDim.x + threadIdx.x;
    int e = idx >> 5, c = idx & 31;
    if (e >= E) return;
    int s = src[e], d = dst[e];
    int half = c >> 4, cc = c & 15;
    float w = dinv[s] * dinv[d];
    float4 v = t4[(size_t)s * 32 + c];
    float* o = out + (size_t)half * N * 64 + (size_t)d * 64 + cc * 4;
    unsafeAtomicAdd(o + 0, v.x * w);
    unsafeAtomicAdd(o + 1, v.y * w);
    unsafeAtomicAdd(o + 2, v.z * w);
    unsafeAtomicAdd(o + 3, v.w * w);
}

// ---------------- launch ----------------
extern "C" void kernel_launch(void* const* d_in, const int* in_sizes, int n_in,
                              void* d_out, int out_size, void* d_ws, size_t ws_size,
                              hipStream_t stream) {
    const float* x   = (const float*)d_in[0];
    const int*   ei  = (const int*)d_in[1];
    const float* W1  = (const float*)d_in[2];
    const float* b1  = (const float*)d_in[3];
    const float* W2  = (const float*)d_in[4];
    const float* b2  = (const float*)d_in[5];
    const float* Wmu = (const float*)d_in[6];
    const float* bmu = (const float*)d_in[7];
    const float* Wls = (const float*)d_in[8];
    const float* bls = (const float*)d_in[9];

    const int N = in_sizes[0] / 128;
    const int E = in_sizes[1] / 2;
    const int* src = ei;
    const int* dst = ei + E;

    float* out = (float*)d_out;

    auto align256 = [](size_t o) { return (o + 255) & ~(size_t)255; };
    const int B1 = (N + SCAN_CHUNK - 1) / SCAN_CHUNK;

    size_t off = 0;
    size_t o_dinv   = off; off = align256(off + (size_t)N * 4);
    size_t o_t      = off; off = align256(off + (size_t)N * 128 * 4);
    size_t o_t2     = off; off = align256(off + (size_t)N * 128 * 4);
    size_t o_rowptr = off; off = align256(off + (size_t)(N + 1) * 4);
    size_t o_cursor = off; off = align256(off + (size_t)N * 4);       // also cnt
    size_t o_bsum   = off; off = align256(off + (size_t)B1 * 4);
    size_t o_col    = off; off = align256(off + (size_t)E * 4);
    size_t need = off;

    float* dinv = (float*)((char*)d_ws + o_dinv);
    float* t    = (float*)((char*)d_ws + o_t);
    float* t2   = (float*)((char*)d_ws + o_t2);

    const int TB = 256;
    int gN = (N + TB - 1) / TB;
    int gE = (E + TB - 1) / TB;
    int ntiles = (N + TILE_R - 1) / TILE_R;

    if (ws_size >= need) {
        int* rowptr = (int*)((char*)d_ws + o_rowptr);
        int* cursor = (int*)((char*)d_ws + o_cursor);
        int* bsum   = (int*)((char*)d_ws + o_bsum);
        int* col    = (int*)((char*)d_ws + o_col);

        // CSR build
        hipMemsetAsync(cursor, 0, (size_t)N * 4, stream);
        cnt_count_kernel<<<gE, TB, 0, stream>>>(dst, cursor, E);
        scan_reduce_kernel<<<B1, TB, 0, stream>>>(cursor, bsum, N);
        scan_bsum_kernel<<<1, 64, 0, stream>>>(bsum, B1, rowptr + N, E);
        scan_write_kernel<<<B1, TB, 0, stream>>>(cursor, bsum, rowptr, cursor, dinv, N);
        csr_fill_kernel<<<gE, TB, 0, stream>>>(src, dst, cursor, col, E);

        // layer 1: t = (x @ W1) * dinv
        gemm128_tiled<<<512, TB, 0, stream>>>(x, W1, nullptr, dinv, t, N, ntiles);
        // layer 2 fused: h1 = relu(agg(t)+b1); t2 = (h1 @ W2) * dinv
        fused_agg_gemm<<<ntiles, TB, 0, stream>>>((const float4*)t, rowptr, col, dinv, b1, W2, nullptr, t2, N);
        // layer 3 fused: h2 = relu(agg(t2)+b2); t = (h2 @ [Wmu|Wls]) * dinv
        fused_agg_gemm<<<ntiles, TB, 0, stream>>>((const float4*)t2, rowptr, col, dinv, b2, Wmu, Wls, t, N);
        // layer 4: final aggregation -> (mu, logstd)
        agg_pull_final_kernel<<<(N + 7) / 8, TB, 0, stream>>>((const float4*)t, rowptr, col, dinv, bmu, bls, (float4*)out, N);
    } else {
        // fallback: atomic scatter path
        int gN32  = (N * 32 + TB - 1) / TB;
        int gE32h = (int)(((long long)E * 32 + TB - 1) / TB);
        deg_init_kernel<<<gN, TB, 0, stream>>>(dinv, N);
        deg_count_kernel<<<gE, TB, 0, stream>>>(dst, dinv, E);
        deg_rsqrt_kernel<<<gN, TB, 0, stream>>>(dinv, N);

        gemm128_kernel<<<2048, TB, 0, stream>>>(x, W1, nullptr, t, N, 0);
        init_self_kernel<<<gN32, TB, 0, stream>>>((const float4*)t, dinv, b1, (float4*)out, N);
        agg_edge_kernel<<<gE32h, TB, 0, stream>>>((const float4*)t, src, dst, dinv, out, E);

        gemm128_kernel<<<2048, TB, 0, stream>>>(out, W2, nullptr, t, N, 1);
        init_self_kernel<<<gN32, TB, 0, stream>>>((const float4*)t, dinv, b2, (float4*)out, N);
        agg_edge_kernel<<<gE32h, TB, 0, stream>>>((const float4*)t, src, dst, dinv, out, E);

        gemm128_kernel<<<2048, TB, 0, stream>>>(out, Wmu, Wls, t, N, 1);
        init_final_kernel<<<gN32, TB, 0, stream>>>((const float4*)t, dinv, bmu, bls, (float4*)out, N);
        agg_edge_final_kernel<<<gE32h, TB, 0, stream>>>((const float4*)t, src, dst, dinv, out, N, E);
    }
}

// Round 7
// 740.189 us; speedup vs baseline: 1.0876x; 1.0161x over previous
//
#include <hip/hip_runtime.h>
#include <hip/hip_bf16.h>

// ---------------- small helpers ----------------
__device__ __forceinline__ float4 f4_fma(float4 a, float s, float4 acc) {
    acc.x = fmaf(a.x, s, acc.x); acc.y = fmaf(a.y, s, acc.y);
    acc.z = fmaf(a.z, s, acc.z); acc.w = fmaf(a.w, s, acc.w);
    return acc;
}
__device__ __forceinline__ float4 f4_add(float4 a, float4 b) {
    return make_float4(a.x + b.x, a.y + b.y, a.z + b.z, a.w + b.w);
}

typedef const __attribute__((address_space(1))) unsigned int* gas_u32;
typedef __attribute__((address_space(3))) unsigned int* las_u32;

__device__ __forceinline__ void gl_lds16(const float* g, float* l) {
    __builtin_amdgcn_global_load_lds((gas_u32)(const void*)g, (las_u32)(void*)l, 16, 0, 0);
}

// ---------------- degree count ----------------
__global__ __launch_bounds__(256) void cnt_count_kernel(const int* __restrict__ dst, int* cnt, int E) {
    int i = blockIdx.x * blockDim.x + threadIdx.x;
    if (i < E) atomicAdd(&cnt[dst[i]], 1);
}

// ---------------- exclusive scan (N ~ 100k) ----------------
#define SCAN_CHUNK 4096  // 256 threads * 16

__global__ __launch_bounds__(256) void scan_reduce_kernel(const int* __restrict__ cnt, int* bsum, int N) {
    __shared__ int sdata[256];
    int base = blockIdx.x * SCAN_CHUNK;
    int s = 0;
    for (int k = 0; k < 16; ++k) {
        int i = base + k * 256 + threadIdx.x;
        if (i < N) s += cnt[i];
    }
    sdata[threadIdx.x] = s;
    __syncthreads();
    for (int off = 128; off > 0; off >>= 1) {
        if (threadIdx.x < off) sdata[threadIdx.x] += sdata[threadIdx.x + off];
        __syncthreads();
    }
    if (threadIdx.x == 0) bsum[blockIdx.x] = sdata[0];
}

__global__ void scan_bsum_kernel(int* bsum, int B, int* rowptr_end, int E) {
    if (threadIdx.x == 0 && blockIdx.x == 0) {
        int run = 0;
        for (int i = 0; i < B; ++i) { int v = bsum[i]; bsum[i] = run; run += v; }
        *rowptr_end = E;  // rowptr[N] = E
    }
}

// also emits dinv (rsqrt(deg)) and cursor (= rowptr copy)
__global__ __launch_bounds__(256) void scan_write_kernel(const int* __restrict__ cnt,
                                                         const int* __restrict__ bsum,
                                                         int* rowptr, int* cursor,
                                                         float* dinv, int N) {
    __shared__ int sdata[256];
    int base = blockIdx.x * SCAN_CHUNK;
    int tbase = base + threadIdx.x * 16;
    int loc[16];
    int s = 0;
    for (int k = 0; k < 16; ++k) {
        int i = tbase + k;
        int v = (i < N) ? cnt[i] : 0;
        loc[k] = s; s += v;
    }
    sdata[threadIdx.x] = s;
    __syncthreads();
    for (int off = 1; off < 256; off <<= 1) {
        int v = sdata[threadIdx.x];
        int add = (threadIdx.x >= off) ? sdata[threadIdx.x - off] : 0;
        __syncthreads();
        sdata[threadIdx.x] = v + add;
        __syncthreads();
    }
    int texcl = (threadIdx.x == 0) ? 0 : sdata[threadIdx.x - 1];
    int boff = bsum[blockIdx.x];
    for (int k = 0; k < 16; ++k) {
        int i = tbase + k;
        if (i < N) {
            int rp = boff + texcl + loc[k];
            rowptr[i] = rp;
            cursor[i] = rp;
            dinv[i] = rsqrtf((float)(cnt[i] + 1));
        }
    }
}

// col-only fill
__global__ __launch_bounds__(256) void csr_fill_kernel(const int* __restrict__ src,
                                                       const int* __restrict__ dst,
                                                       int* cursor, int* __restrict__ col,
                                                       int E) {
    int e = blockIdx.x * blockDim.x + threadIdx.x;
    if (e >= E) return;
    int s = src[e], d = dst[e];
    int pos = atomicAdd(&cursor[d], 1);
    col[pos] = s;
}

// ---------------- register-tiled GEMM: t[N][128] = (h[N][128] @ W) * dinv[row] ----------------
#define TILE_R 64

__global__ __launch_bounds__(256, 2) void gemm128_tiled(const float* __restrict__ h,
                                                        const float* __restrict__ Wa,
                                                        const float* __restrict__ Wb,
                                                        const float* __restrict__ dinv,
                                                        float* __restrict__ t,
                                                        int N, int ntiles) {
    __shared__ float hl[2][TILE_R * 128];

    const int lane = threadIdx.x & 63;
    const int wav  = threadIdx.x >> 6;
    const int jf4  = threadIdx.x & 31;
    const int rg   = threadIdx.x >> 5;

    const float* wptr;
    int wstride;
    if (Wb) { wptr = (jf4 < 16) ? (Wa + jf4 * 4) : (Wb + (jf4 - 16) * 4); wstride = 64; }
    else    { wptr = Wa + jf4 * 4; wstride = 128; }

    auto stage = [&](int buf, long long tile) {
        if (tile >= ntiles) return;
        long long row0 = tile * TILE_R;
        if (row0 + TILE_R <= N) {
            const float* gbase = h + row0 * 128 + (size_t)wav * (16 * 128) + lane * 4;
            float* lbase = &hl[buf][wav * (16 * 128)];
            #pragma unroll
            for (int m = 0; m < 8; ++m)
                gl_lds16(gbase + m * 256, lbase + m * 256);
        } else {
            for (int i = threadIdx.x; i < TILE_R * 32; i += 256) {
                int rl = i >> 5, k4 = i & 31;
                long long row = row0 + rl;
                float4 v = (row < N) ? ((const float4*)h)[row * 32 + k4]
                                     : make_float4(0.f, 0.f, 0.f, 0.f);
                *(float4*)&hl[buf][rl * 128 + k4 * 4] = v;
            }
        }
    };

    long long tile = blockIdx.x;
    stage(0, tile);
    __syncthreads();
    int cur = 0;

    for (; tile < ntiles; tile += gridDim.x) {
        stage(cur ^ 1, tile + gridDim.x);

        float4 acc[8];
        #pragma unroll
        for (int rr = 0; rr < 8; ++rr) acc[rr] = make_float4(0.f, 0.f, 0.f, 0.f);

        const float* hb = &hl[cur][rg * 8 * 128];
        #pragma unroll 4
        for (int k = 0; k < 128; k += 4) {
            float4 w0 = *(const float4*)&wptr[(size_t)(k + 0) * wstride];
            float4 w1 = *(const float4*)&wptr[(size_t)(k + 1) * wstride];
            float4 w2 = *(const float4*)&wptr[(size_t)(k + 2) * wstride];
            float4 w3 = *(const float4*)&wptr[(size_t)(k + 3) * wstride];
            #pragma unroll
            for (int rr = 0; rr < 8; ++rr) {
                float4 hv = *(const float4*)&hb[rr * 128 + k];
                acc[rr] = f4_fma(w0, hv.x, acc[rr]);
                acc[rr] = f4_fma(w1, hv.y, acc[rr]);
                acc[rr] = f4_fma(w2, hv.z, acc[rr]);
                acc[rr] = f4_fma(w3, hv.w, acc[rr]);
            }
        }

        long long row0 = tile * TILE_R;
        #pragma unroll
        for (int rr = 0; rr < 8; ++rr) {
            long long row = row0 + rg * 8 + rr;
            if (row < N) {
                float di = dinv[row];
                float4 r = acc[rr];
                r.x *= di; r.y *= di; r.z *= di; r.w *= di;
                ((float4*)t)[row * 32 + jf4] = r;
            }
        }
        __syncthreads();
        cur ^= 1;
    }
}

// ---------------- fused agg(layer k) + gemm(layer k+1) ----------------
// Block owns 64 dst rows. Phase A: pull-aggregate + relu into LDS.
// Phase B: register-tiled GEMM from LDS; t_out = (h @ [Wa|Wb]) * dinv[row].
// NO block barrier between phases: group grp writes LDS rows grp*8..grp*8+7 in
// phase A and (as rg==grp) reads exactly those rows in phase B -- producer and
// consumer are the same wave, so waves proceed independently (no straggler
// wait; gather-phase waves overlap FMA-phase waves on the CU).
__global__ __launch_bounds__(256) void fused_agg_gemm(const float4* __restrict__ t4,
                                                      const int* __restrict__ rowptr,
                                                      const int* __restrict__ col,
                                                      const float* __restrict__ dinv,
                                                      const float* __restrict__ bvec,
                                                      const float* __restrict__ Wa,
                                                      const float* __restrict__ Wb,
                                                      float* __restrict__ tout,
                                                      int N) {
    __shared__ float hl[TILE_R * 128];  // 32 KB

    const int grp = threadIdx.x >> 5;   // 0..7
    const int c   = threadIdx.x & 31;   // float4 col
    const long long row0 = (long long)blockIdx.x * TILE_R;

    // Phase A: each 32-lane group aggregates its 8 rows into its LDS rows (with relu)
    float4 bb = ((const float4*)bvec)[c];
    #pragma unroll 1
    for (int r = 0; r < 8; ++r) {
        long long v = row0 + grp * 8 + r;
        float4 res;
        if (v < N) {
            int beg = rowptr[v], end = rowptr[v + 1];
            float4 acc0 = t4[(size_t)v * 32 + c];  // self-loop (pre-scaled)
            float4 acc1 = make_float4(0.f, 0.f, 0.f, 0.f);
            float4 acc2 = make_float4(0.f, 0.f, 0.f, 0.f);
            float4 acc3 = make_float4(0.f, 0.f, 0.f, 0.f);
            int e = beg;
            for (; e + 7 < end; e += 8) {
                int s0 = col[e],     s1 = col[e + 1], s2 = col[e + 2], s3 = col[e + 3];
                int s4 = col[e + 4], s5 = col[e + 5], s6 = col[e + 6], s7 = col[e + 7];
                float4 v0 = t4[(size_t)s0 * 32 + c];
                float4 v1 = t4[(size_t)s1 * 32 + c];
                float4 v2 = t4[(size_t)s2 * 32 + c];
                float4 v3 = t4[(size_t)s3 * 32 + c];
                float4 v4 = t4[(size_t)s4 * 32 + c];
                float4 v5 = t4[(size_t)s5 * 32 + c];
                float4 v6 = t4[(size_t)s6 * 32 + c];
                float4 v7 = t4[(size_t)s7 * 32 + c];
                acc0 = f4_add(acc0, v0); acc1 = f4_add(acc1, v1);
                acc2 = f4_add(acc2, v2); acc3 = f4_add(acc3, v3);
                acc0 = f4_add(acc0, v4); acc1 = f4_add(acc1, v5);
                acc2 = f4_add(acc2, v6); acc3 = f4_add(acc3, v7);
            }
            for (; e + 3 < end; e += 4) {
                int s0 = col[e], s1 = col[e + 1], s2 = col[e + 2], s3 = col[e + 3];
                acc0 = f4_add(acc0, t4[(size_t)s0 * 32 + c]);
                acc1 = f4_add(acc1, t4[(size_t)s1 * 32 + c]);
                acc2 = f4_add(acc2, t4[(size_t)s2 * 32 + c]);
                acc3 = f4_add(acc3, t4[(size_t)s3 * 32 + c]);
            }
            for (; e < end; ++e) acc0 = f4_add(acc0, t4[(size_t)col[e] * 32 + c]);
            float di = dinv[v];
            float4 s = f4_add(f4_add(acc0, acc1), f4_add(acc2, acc3));
            res = f4_fma(s, di, bb);
            res.x = fmaxf(res.x, 0.f); res.y = fmaxf(res.y, 0.f);
            res.z = fmaxf(res.z, 0.f); res.w = fmaxf(res.w, 0.f);
        } else {
            res = make_float4(0.f, 0.f, 0.f, 0.f);
        }
        *(float4*)&hl[(grp * 8 + r) * 128 + c * 4] = res;
    }
    // (no __syncthreads: see kernel comment -- intra-wave LDS RAW dependency only)

    // Phase B: GEMM from LDS (thread: 8 rows x 4 cols, rows rg*8..rg*8+7 == grp's rows)
    const int jf4 = c;
    const int rg  = grp;
    const float* wptr;
    int wstride;
    if (Wb) { wptr = (jf4 < 16) ? (Wa + jf4 * 4) : (Wb + (jf4 - 16) * 4); wstride = 64; }
    else    { wptr = Wa + jf4 * 4; wstride = 128; }

    float4 acc[8];
    #pragma unroll
    for (int rr = 0; rr < 8; ++rr) acc[rr] = make_float4(0.f, 0.f, 0.f, 0.f);

    const float* hb = &hl[rg * 8 * 128];
    #pragma unroll 4
    for (int k = 0; k < 128; k += 4) {
        float4 w0 = *(const float4*)&wptr[(size_t)(k + 0) * wstride];
        float4 w1 = *(const float4*)&wptr[(size_t)(k + 1) * wstride];
        float4 w2 = *(const float4*)&wptr[(size_t)(k + 2) * wstride];
        float4 w3 = *(const float4*)&wptr[(size_t)(k + 3) * wstride];
        #pragma unroll
        for (int rr = 0; rr < 8; ++rr) {
            float4 hv = *(const float4*)&hb[rr * 128 + k];
            acc[rr] = f4_fma(w0, hv.x, acc[rr]);
            acc[rr] = f4_fma(w1, hv.y, acc[rr]);
            acc[rr] = f4_fma(w2, hv.z, acc[rr]);
            acc[rr] = f4_fma(w3, hv.w, acc[rr]);
        }
    }

    #pragma unroll
    for (int rr = 0; rr < 8; ++rr) {
        long long row = row0 + rg * 8 + rr;
        if (row < N) {
            float di = dinv[row];
            float4 r = acc[rr];
            r.x *= di; r.y *= di; r.z *= di; r.w *= di;
            ((float4*)tout)[row * 32 + jf4] = r;
        }
    }
}

// final layer: cols 0..63 -> mu, 64..127 -> logstd (split output)
__global__ __launch_bounds__(256) void agg_pull_final_kernel(const float4* __restrict__ t4,
                                                             const int* __restrict__ rowptr,
                                                             const int* __restrict__ col,
                                                             const float* __restrict__ dinv,
                                                             const float* __restrict__ bmu,
                                                             const float* __restrict__ bls,
                                                             float4* __restrict__ out4,
                                                             int N) {
    int v = blockIdx.x * 8 + (threadIdx.x >> 5);
    int c = threadIdx.x & 31;
    if (v >= N) return;
    int half = c >> 4, cc = c & 15;
    int beg = rowptr[v], end = rowptr[v + 1];
    float4 acc0 = t4[(size_t)v * 32 + c];
    float4 acc1 = make_float4(0.f, 0.f, 0.f, 0.f);
    float4 acc2 = make_float4(0.f, 0.f, 0.f, 0.f);
    float4 acc3 = make_float4(0.f, 0.f, 0.f, 0.f);
    int e = beg;
    for (; e + 7 < end; e += 8) {
        int s0 = col[e],     s1 = col[e + 1], s2 = col[e + 2], s3 = col[e + 3];
        int s4 = col[e + 4], s5 = col[e + 5], s6 = col[e + 6], s7 = col[e + 7];
        float4 v0 = t4[(size_t)s0 * 32 + c];
        float4 v1 = t4[(size_t)s1 * 32 + c];
        float4 v2 = t4[(size_t)s2 * 32 + c];
        float4 v3 = t4[(size_t)s3 * 32 + c];
        float4 v4 = t4[(size_t)s4 * 32 + c];
        float4 v5 = t4[(size_t)s5 * 32 + c];
        float4 v6 = t4[(size_t)s6 * 32 + c];
        float4 v7 = t4[(size_t)s7 * 32 + c];
        acc0 = f4_add(acc0, v0); acc1 = f4_add(acc1, v1);
        acc2 = f4_add(acc2, v2); acc3 = f4_add(acc3, v3);
        acc0 = f4_add(acc0, v4); acc1 = f4_add(acc1, v5);
        acc2 = f4_add(acc2, v6); acc3 = f4_add(acc3, v7);
    }
    for (; e + 3 < end; e += 4) {
        int s0 = col[e], s1 = col[e + 1], s2 = col[e + 2], s3 = col[e + 3];
        acc0 = f4_add(acc0, t4[(size_t)s0 * 32 + c]);
        acc1 = f4_add(acc1, t4[(size_t)s1 * 32 + c]);
        acc2 = f4_add(acc2, t4[(size_t)s2 * 32 + c]);
        acc3 = f4_add(acc3, t4[(size_t)s3 * 32 + c]);
    }
    for (; e < end; ++e) acc0 = f4_add(acc0, t4[(size_t)col[e] * 32 + c]);
    float di = dinv[v];
    float4 s = f4_add(f4_add(acc0, acc1), f4_add(acc2, acc3));
    float4 bb = half ? ((const float4*)bls)[cc] : ((const float4*)bmu)[cc];
    out4[(size_t)half * N * 16 + (size_t)v * 16 + cc] = f4_fma(s, di, bb);
}

// ---------------- fallback (atomic scatter) kernels ----------------
__global__ __launch_bounds__(256) void deg_init_kernel(float* deg, int N) {
    int i = blockIdx.x * blockDim.x + threadIdx.x;
    if (i < N) deg[i] = 1.0f;
}
__global__ __launch_bounds__(256) void deg_count_kernel(const int* __restrict__ dst, float* deg, int E) {
    int i = blockIdx.x * blockDim.x + threadIdx.x;
    if (i < E) unsafeAtomicAdd(&deg[dst[i]], 1.0f);
}
__global__ __launch_bounds__(256) void deg_rsqrt_kernel(float* deg, int N) {
    int i = blockIdx.x * blockDim.x + threadIdx.x;
    if (i < N) deg[i] = rsqrtf(deg[i]);
}
__global__ __launch_bounds__(256) void gemm128_kernel(const float* __restrict__ h,
                                                      const float* __restrict__ Wa,
                                                      const float* __restrict__ Wb,
                                                      float* __restrict__ t,
                                                      int N, int relu) {
    __shared__ float Wl[128 * 128];
    __shared__ float hl[2][128];
    for (int i = threadIdx.x; i < 128 * 128; i += 256) {
        int k = i >> 7, j = i & 127;
        float w;
        if (Wb) w = (j < 64) ? Wa[k * 64 + j] : Wb[k * 64 + (j - 64)];
        else    w = Wa[i];
        Wl[i] = w;
    }
    __syncthreads();
    int col = threadIdx.x & 127;
    int r   = threadIdx.x >> 7;
    for (long long pair = blockIdx.x; pair * 2 < N; pair += gridDim.x) {
        int row0 = (int)(pair * 2);
        {
            int rr = threadIdx.x >> 7, k = threadIdx.x & 127;
            int row = row0 + rr;
            float v = (row < N) ? h[(size_t)row * 128 + k] : 0.0f;
            if (relu) v = fmaxf(v, 0.0f);
            hl[rr][k] = v;
        }
        __syncthreads();
        float acc = 0.0f;
        #pragma unroll
        for (int k = 0; k < 128; k += 4) {
            float4 hv = *(const float4*)&hl[r][k];
            acc += hv.x * Wl[(k + 0) * 128 + col];
            acc += hv.y * Wl[(k + 1) * 128 + col];
            acc += hv.z * Wl[(k + 2) * 128 + col];
            acc += hv.w * Wl[(k + 3) * 128 + col];
        }
        int row = row0 + r;
        if (row < N) t[(size_t)row * 128 + col] = acc;
        __syncthreads();
    }
}
__global__ __launch_bounds__(256) void init_self_kernel(const float4* __restrict__ t4,
                                                        const float* __restrict__ dinv,
                                                        const float* __restrict__ b,
                                                        float4* __restrict__ out, int N) {
    int idx = blockIdx.x * blockDim.x + threadIdx.x;
    int v = idx >> 5, c = idx & 31;
    if (v >= N) return;
    float di = dinv[v];
    float s = di * di;
    float4 x = t4[(size_t)v * 32 + c];
    float4 bb = ((const float4*)b)[c];
    out[(size_t)v * 32 + c] = make_float4(fmaf(x.x, s, bb.x), fmaf(x.y, s, bb.y),
                                          fmaf(x.z, s, bb.z), fmaf(x.w, s, bb.w));
}
__global__ __launch_bounds__(256) void init_final_kernel(const float4* __restrict__ t4,
                                                         const float* __restrict__ dinv,
                                                         const float* __restrict__ bmu,
                                                         const float* __restrict__ bls,
                                                         float4* __restrict__ out4, int N) {
    int idx = blockIdx.x * blockDim.x + threadIdx.x;
    int v = idx >> 5, c = idx & 31;
    if (v >= N) return;
    int half = c >> 4, cc = c & 15;
    float di = dinv[v];
    float s = di * di;
    float4 x = t4[(size_t)v * 32 + c];
    float4 bb = half ? ((const float4*)bls)[cc] : ((const float4*)bmu)[cc];
    out4[(size_t)half * N * 16 + (size_t)v * 16 + cc] =
        make_float4(fmaf(x.x, s, bb.x), fmaf(x.y, s, bb.y),
                    fmaf(x.z, s, bb.z), fmaf(x.w, s, bb.w));
}
__global__ __launch_bounds__(256) void agg_edge_kernel(const float4* __restrict__ t4,
                                                       const int* __restrict__ src,
                                                       const int* __restrict__ dst,
                                                       const float* __restrict__ dinv,
                                                       float* __restrict__ out, int E) {
    int idx = blockIdx.x * blockDim.x + threadIdx.x;
    int e = idx >> 5, c = idx & 31;
    if (e >= E) return;
    int s = src[e], d = dst[e];
    float w = dinv[s] * dinv[d];
    float4 v = t4[(size_t)s * 32 + c];
    float* o = out + (size_t)d * 128 + c * 4;
    unsafeAtomicAdd(o + 0, v.x * w);
    unsafeAtomicAdd(o + 1, v.y * w);
    unsafeAtomicAdd(o + 2, v.z * w);
    unsafeAtomicAdd(o + 3, v.w * w);
}
__global__ __launch_bounds__(256) void agg_edge_final_kernel(const float4* __restrict__ t4,
                                                             const int* __restrict__ src,
                                                             const int* __restrict__ dst,
                                                             const float* __restrict__ dinv,
                                                             float* __restrict__ out, int N, int E) {
    int idx = blockIdx.x * blockDim.x + threadIdx.x;
    int e = idx >> 5, c = idx & 31;
    if (e >= E) return;
    int s = src[e], d = dst[e];
    int half = c >> 4, cc = c & 15;
    float w = dinv[s] * dinv[d];
    float4 v = t4[(size_t)s * 32 + c];
    float* o = out + (size_t)half * N * 64 + (size_t)d * 64 + cc * 4;
    unsafeAtomicAdd(o + 0, v.x * w);
    unsafeAtomicAdd(o + 1, v.y * w);
    unsafeAtomicAdd(o + 2, v.z * w);
    unsafeAtomicAdd(o + 3, v.w * w);
}

// ---------------- launch ----------------
extern "C" void kernel_launch(void* const* d_in, const int* in_sizes, int n_in,
                              void* d_out, int out_size, void* d_ws, size_t ws_size,
                              hipStream_t stream) {
    const float* x   = (const float*)d_in[0];
    const int*   ei  = (const int*)d_in[1];
    const float* W1  = (const float*)d_in[2];
    const float* b1  = (const float*)d_in[3];
    const float* W2  = (const float*)d_in[4];
    const float* b2  = (const float*)d_in[5];
    const float* Wmu = (const float*)d_in[6];
    const float* bmu = (const float*)d_in[7];
    const float* Wls = (const float*)d_in[8];
    const float* bls = (const float*)d_in[9];

    const int N = in_sizes[0] / 128;
    const int E = in_sizes[1] / 2;
    const int* src = ei;
    const int* dst = ei + E;

    float* out = (float*)d_out;

    auto align256 = [](size_t o) { return (o + 255) & ~(size_t)255; };
    const int B1 = (N + SCAN_CHUNK - 1) / SCAN_CHUNK;

    size_t off = 0;
    size_t o_dinv   = off; off = align256(off + (size_t)N * 4);
    size_t o_t      = off; off = align256(off + (size_t)N * 128 * 4);
    size_t o_t2     = off; off = align256(off + (size_t)N * 128 * 4);
    size_t o_rowptr = off; off = align256(off + (size_t)(N + 1) * 4);
    size_t o_cursor = off; off = align256(off + (size_t)N * 4);       // also cnt
    size_t o_bsum   = off; off = align256(off + (size_t)B1 * 4);
    size_t o_col    = off; off = align256(off + (size_t)E * 4);
    size_t need = off;

    float* dinv = (float*)((char*)d_ws + o_dinv);
    float* t    = (float*)((char*)d_ws + o_t);
    float* t2   = (float*)((char*)d_ws + o_t2);

    const int TB = 256;
    int gN = (N + TB - 1) / TB;
    int gE = (E + TB - 1) / TB;
    int ntiles = (N + TILE_R - 1) / TILE_R;

    if (ws_size >= need) {
        int* rowptr = (int*)((char*)d_ws + o_rowptr);
        int* cursor = (int*)((char*)d_ws + o_cursor);
        int* bsum   = (int*)((char*)d_ws + o_bsum);
        int* col    = (int*)((char*)d_ws + o_col);

        // CSR build
        hipMemsetAsync(cursor, 0, (size_t)N * 4, stream);
        cnt_count_kernel<<<gE, TB, 0, stream>>>(dst, cursor, E);
        scan_reduce_kernel<<<B1, TB, 0, stream>>>(cursor, bsum, N);
        scan_bsum_kernel<<<1, 64, 0, stream>>>(bsum, B1, rowptr + N, E);
        scan_write_kernel<<<B1, TB, 0, stream>>>(cursor, bsum, rowptr, cursor, dinv, N);
        csr_fill_kernel<<<gE, TB, 0, stream>>>(src, dst, cursor, col, E);

        // layer 1: t = (x @ W1) * dinv
        gemm128_tiled<<<512, TB, 0, stream>>>(x, W1, nullptr, dinv, t, N, ntiles);
        // layer 2 fused: h1 = relu(agg(t)+b1); t2 = (h1 @ W2) * dinv
        fused_agg_gemm<<<ntiles, TB, 0, stream>>>((const float4*)t, rowptr, col, dinv, b1, W2, nullptr, t2, N);
        // layer 3 fused: h2 = relu(agg(t2)+b2); t = (h2 @ [Wmu|Wls]) * dinv
        fused_agg_gemm<<<ntiles, TB, 0, stream>>>((const float4*)t2, rowptr, col, dinv, b2, Wmu, Wls, t, N);
        // layer 4: final aggregation -> (mu, logstd)
        agg_pull_final_kernel<<<(N + 7) / 8, TB, 0, stream>>>((const float4*)t, rowptr, col, dinv, bmu, bls, (float4*)out, N);
    } else {
        // fallback: atomic scatter path
        int gN32  = (N * 32 + TB - 1) / TB;
        int gE32h = (int)(((long long)E * 32 + TB - 1) / TB);
        deg_init_kernel<<<gN, TB, 0, stream>>>(dinv, N);
        deg_count_kernel<<<gE, TB, 0, stream>>>(dst, dinv, E);
        deg_rsqrt_kernel<<<gN, TB, 0, stream>>>(dinv, N);

        gemm128_kernel<<<2048, TB, 0, stream>>>(x, W1, nullptr, t, N, 0);
        init_self_kernel<<<gN32, TB, 0, stream>>>((const float4*)t, dinv, b1, (float4*)out, N);
        agg_edge_kernel<<<gE32h, TB, 0, stream>>>((const float4*)t, src, dst, dinv, out, E);

        gemm128_kernel<<<2048, TB, 0, stream>>>(out, W2, nullptr, t, N, 1);
        init_self_kernel<<<gN32, TB, 0, stream>>>((const float4*)t, dinv, b2, (float4*)out, N);
        agg_edge_kernel<<<gE32h, TB, 0, stream>>>((const float4*)t, src, dst, dinv, out, E);

        gemm128_kernel<<<2048, TB, 0, stream>>>(out, Wmu, Wls, t, N, 1);
        init_final_kernel<<<gN32, TB, 0, stream>>>((const float4*)t, dinv, bmu, bls, (float4*)out, N);
        agg_edge_final_kernel<<<gE32h, TB, 0, stream>>>((const float4*)t, src, dst, dinv, out, N, E);
    }
}